// Round 1
// baseline (5333.050 us; speedup 1.0000x reference)
//
#include <hip/hip_runtime.h>
#include <hip/hip_bf16.h>
#include <math.h>

// ---------------------------------------------------------------------------
// PriorEnhancedMindEncoder forward, fp32.
// Shapes: B=64, N=360, DH=256, H=8. dh(GAT0/1)=32, dh(GAT2)=256.
//
// Dead-code: adj_norm is strictly positive -> GAT mask all-true -> the whole
// group_prior/Wp1/Wp2/adjacency branch never influences the outputs. Skipped.
//
// Fusion: nf = mind@(Wnp@Wrf_top) + roi@Wrf_bot + (bnp@Wrf_top+brf), LN+GELU.
// ---------------------------------------------------------------------------

#define B_ 64
#define N_ 360
#define D_ 256
#define H_ 8
#define ROWS_ (B_ * N_)   // 23040

__device__ __forceinline__ float gelu_f(float x) {
    return 0.5f * x * (1.f + erff(x * 0.70710678118654752440f));
}

// ---------------------------------------------------------------------------
// Generic tiled fp32 GEMM: C[M,N] = A1[M,K1]@B1[K1,N] (+ A2[M,K2]@B2[K2,N]) + bias
// 64x64 tile, 256 threads, 4x4 microtile per thread.
// ---------------------------------------------------------------------------
__global__ __launch_bounds__(256) void gemm_dual(
    const float* __restrict__ A1, const float* __restrict__ B1, int K1, int lda1, int ldb1,
    const float* __restrict__ A2, const float* __restrict__ B2, int K2, int lda2, int ldb2,
    const float* __restrict__ bias, float* __restrict__ C, int M, int N, int ldc)
{
    __shared__ float As[16][68];   // [k][m], padded: 16B-aligned float4 reads
    __shared__ float Bs[16][64];   // [k][n]
    const int tid = threadIdx.x;
    const int bm = blockIdx.y * 64;
    const int bn = blockIdx.x * 64;
    const int tr = (tid >> 4) << 2;   // 0..60
    const int tc = (tid & 15) << 2;   // 0..60
    float acc[4][4] = {};

    for (int pass = 0; pass < 2; ++pass) {
        const float* A = pass ? A2 : A1;
        const float* Bm = pass ? B2 : B1;
        const int K = pass ? K2 : K1;
        const int lda = pass ? lda2 : lda1;
        const int ldb = pass ? ldb2 : ldb1;
        if (A == nullptr) continue;
        for (int k0 = 0; k0 < K; k0 += 16) {
            #pragma unroll
            for (int i = 0; i < 4; ++i) {
                int idx = tid + i * 256;          // 0..1023
                int m = idx >> 4, k = idx & 15;
                int gr = bm + m, gk = k0 + k;
                float v = 0.f;
                if (gr < M && gk < K) v = A[(size_t)gr * lda + gk];
                As[k][m] = v;
            }
            #pragma unroll
            for (int i = 0; i < 4; ++i) {
                int idx = tid + i * 256;
                int k = idx >> 6, c = idx & 63;
                int gk = k0 + k, gc = bn + c;
                float v = 0.f;
                if (gk < K && gc < N) v = Bm[(size_t)gk * ldb + gc];
                Bs[k][c] = v;
            }
            __syncthreads();
            #pragma unroll
            for (int k = 0; k < 16; ++k) {
                float4 av = *(const float4*)&As[k][tr];
                float4 bv = *(const float4*)&Bs[k][tc];
                acc[0][0] += av.x * bv.x; acc[0][1] += av.x * bv.y;
                acc[0][2] += av.x * bv.z; acc[0][3] += av.x * bv.w;
                acc[1][0] += av.y * bv.x; acc[1][1] += av.y * bv.y;
                acc[1][2] += av.y * bv.z; acc[1][3] += av.y * bv.w;
                acc[2][0] += av.z * bv.x; acc[2][1] += av.z * bv.y;
                acc[2][2] += av.z * bv.z; acc[2][3] += av.z * bv.w;
                acc[3][0] += av.w * bv.x; acc[3][1] += av.w * bv.y;
                acc[3][2] += av.w * bv.z; acc[3][3] += av.w * bv.w;
            }
            __syncthreads();
        }
    }

    #pragma unroll
    for (int i = 0; i < 4; ++i) {
        int r = bm + tr + i;
        if (r >= M) break;
        #pragma unroll
        for (int j = 0; j < 4; ++j) {
            int c = bn + tc + j;
            if (c < N) {
                float v = acc[i][j];
                if (bias) v += bias[c];
                C[(size_t)r * ldc + c] = v;
            }
        }
    }
}

// bias_comb[c] = brf[c] + sum_k bnp[k] * Wrf[k, c]   (top half of Wrf)
__global__ __launch_bounds__(256) void biascomb_kernel(
    const float* __restrict__ bnp, const float* __restrict__ Wrf,
    const float* __restrict__ brf, float* __restrict__ bcomb)
{
    int c = threadIdx.x;
    float acc = brf[c];
    for (int k = 0; k < 256; ++k) acc += bnp[k] * Wrf[k * 256 + c];
    bcomb[c] = acc;
}

// LayerNorm(eps=1e-5) + exact GELU, in-place on rows of 256. 1 wave per row.
__global__ __launch_bounds__(64) void ln_gelu_kernel(
    float* __restrict__ x, const float* __restrict__ g, const float* __restrict__ b)
{
    const size_t row = blockIdx.x;
    const int t = threadIdx.x;
    float4 v = *(const float4*)&x[row * 256 + t * 4];
    float s = v.x + v.y + v.z + v.w;
    #pragma unroll
    for (int m = 1; m < 64; m <<= 1) s += __shfl_xor(s, m);
    float mean = s * (1.f / 256.f);
    float dx = v.x - mean, dy = v.y - mean, dz = v.z - mean, dw = v.w - mean;
    float q = dx * dx + dy * dy + dz * dz + dw * dw;
    #pragma unroll
    for (int m = 1; m < 64; m <<= 1) q += __shfl_xor(q, m);
    float rstd = 1.f / sqrtf(q * (1.f / 256.f) + 1e-5f);
    float4 gg = *(const float4*)&g[t * 4];
    float4 bb = *(const float4*)&b[t * 4];
    float4 r;
    r.x = gelu_f(dx * rstd * gg.x + bb.x);
    r.y = gelu_f(dy * rstd * gg.y + bb.y);
    r.z = gelu_f(dz * rstd * gg.z + bb.z);
    r.w = gelu_f(dw * rstd * gg.w + bb.w);
    *(float4*)&x[row * 256 + t * 4] = r;
}

// ei/ej: per row (b,n): ei[h] = ht[row,h,:] . a[h,:dh], ej[h] = ht[row,h,:] . a[h,dh:]
template <int DH>
__global__ __launch_bounds__(64) void eiej_kernel(
    const float* __restrict__ ht, const float* __restrict__ a,
    float* __restrict__ ei, float* __restrict__ ej)
{
    const size_t row = blockIdx.x;
    const int t = threadIdx.x;
    constexpr int E = (H_ * DH) / 64;
    const int h = t >> 3;
    const int d0 = (t & 7) * E;
    const float* hp = ht + row * (H_ * DH) + h * DH + d0;
    const float* ap = a + h * 2 * DH + d0;
    float se = 0.f, sj = 0.f;
    #pragma unroll
    for (int i = 0; i < E; ++i) {
        float x = hp[i];
        se += x * ap[i];
        sj += x * ap[DH + i];
    }
    se += __shfl_xor(se, 1); sj += __shfl_xor(sj, 1);
    se += __shfl_xor(se, 2); sj += __shfl_xor(sj, 2);
    se += __shfl_xor(se, 4); sj += __shfl_xor(sj, 4);
    if ((t & 7) == 0) {
        ei[row * H_ + h] = se;
        ej[row * H_ + h] = sj;
    }
}

// GAT attention + aggregation for one (b,h), 32 query rows per block.
// scores = leakyrelu(ei[n] + ej[m]) (mask all-true); softmax over m; out = alpha @ V.
template <int DH>
__global__ __launch_bounds__(256) void gat_agg(
    const float* __restrict__ ht, const float* __restrict__ ei,
    const float* __restrict__ ej, float* __restrict__ out)
{
    constexpr int HD = H_ * DH;
    __shared__ float ejs[N_];
    __shared__ float eis[32];
    __shared__ float sc[32][N_];
    const int tid = threadIdx.x;
    const int bh = blockIdx.y;
    const int b = bh >> 3, h = bh & 7;
    const int n0 = blockIdx.x * 32;
    const int nrows = min(32, N_ - n0);

    for (int m = tid; m < N_; m += 256) ejs[m] = ej[(b * N_ + m) * H_ + h];
    if (tid < 32) eis[tid] = (tid < nrows) ? ei[(size_t)(b * N_ + n0 + tid) * H_ + h] : 0.f;
    __syncthreads();

    const int r = tid >> 3, sub = tid & 7;
    const float eir = eis[r];
    float rmax = -1e30f;
    for (int m = sub; m < N_; m += 8) {
        float s = eir + ejs[m];
        s = s > 0.f ? s : 0.2f * s;
        sc[r][m] = s;
        rmax = fmaxf(rmax, s);
    }
    rmax = fmaxf(rmax, __shfl_xor(rmax, 1));
    rmax = fmaxf(rmax, __shfl_xor(rmax, 2));
    rmax = fmaxf(rmax, __shfl_xor(rmax, 4));
    float rsum = 0.f;
    for (int m = sub; m < N_; m += 8) {
        float p = __expf(sc[r][m] - rmax);
        sc[r][m] = p;
        rsum += p;
    }
    rsum += __shfl_xor(rsum, 1);
    rsum += __shfl_xor(rsum, 2);
    rsum += __shfl_xor(rsum, 4);
    const float rinv = 1.f / rsum;
    for (int m = sub; m < N_; m += 8) sc[r][m] *= rinv;
    __syncthreads();

    if (DH == 256) {
        const int c = tid;
        const float* V = ht + (size_t)b * N_ * HD + h * DH + c;
        float acc[32];
        #pragma unroll
        for (int i = 0; i < 32; ++i) acc[i] = 0.f;
        for (int m = 0; m < N_; m += 4) {
            float v0 = V[(size_t)(m + 0) * HD];
            float v1 = V[(size_t)(m + 1) * HD];
            float v2 = V[(size_t)(m + 2) * HD];
            float v3 = V[(size_t)(m + 3) * HD];
            #pragma unroll
            for (int i = 0; i < 32; ++i) {
                float4 s4 = *(const float4*)&sc[i][m];
                acc[i] += s4.x * v0 + s4.y * v1 + s4.z * v2 + s4.w * v3;
            }
        }
        for (int i = 0; i < nrows; ++i)
            out[(size_t)(b * N_ + n0 + i) * HD + h * DH + c] = acc[i];
    } else {
        const int c = tid & (DH - 1);
        const int rg = tid >> 5;           // 8 groups x 4 rows (DH==32)
        const float* V = ht + (size_t)b * N_ * HD + h * DH + c;
        float acc[4] = {};
        for (int m = 0; m < N_; m += 4) {
            float v0 = V[(size_t)(m + 0) * HD];
            float v1 = V[(size_t)(m + 1) * HD];
            float v2 = V[(size_t)(m + 2) * HD];
            float v3 = V[(size_t)(m + 3) * HD];
            #pragma unroll
            for (int i = 0; i < 4; ++i) {
                float4 s4 = *(const float4*)&sc[rg * 4 + i][m];
                acc[i] += s4.x * v0 + s4.y * v1 + s4.z * v2 + s4.w * v3;
            }
        }
        #pragma unroll
        for (int i = 0; i < 4; ++i) {
            int rr = rg * 4 + i;
            if (rr < nrows)
                out[(size_t)(b * N_ + n0 + rr) * HD + h * DH + c] = acc[i];
        }
    }
}

// row L2 norm of h rows (256 wide), 1 wave per row
__global__ __launch_bounds__(64) void rownorm_kernel(
    const float* __restrict__ h, float* __restrict__ nrm)
{
    const size_t row = blockIdx.x;
    const int t = threadIdx.x;
    float4 v = *(const float4*)&h[row * 256 + t * 4];
    float s = v.x * v.x + v.y * v.y + v.z * v.z + v.w * v.w;
    #pragma unroll
    for (int m = 1; m < 64; m <<= 1) s += __shfl_xor(s, m);
    if (t == 0) nrm[row] = sqrtf(s);
}

// softmax over N=360 per batch, 1 wave per batch
__global__ __launch_bounds__(64) void softmax_n_kernel(
    const float* __restrict__ nrm, float* __restrict__ attn)
{
    const int b = blockIdx.x;
    const int t = threadIdx.x;
    float v[6];
    float mx = -1e30f;
    #pragma unroll
    for (int i = 0; i < 6; ++i) {
        int m = t + i * 64;
        v[i] = (m < N_) ? nrm[b * N_ + m] : -1e30f;
        mx = fmaxf(mx, v[i]);
    }
    #pragma unroll
    for (int m = 1; m < 64; m <<= 1) mx = fmaxf(mx, __shfl_xor(mx, m));
    float s = 0.f;
    #pragma unroll
    for (int i = 0; i < 6; ++i) {
        int m = t + i * 64;
        float p = (m < N_) ? __expf(v[i] - mx) : 0.f;
        v[i] = p;
        s += p;
    }
    #pragma unroll
    for (int m = 1; m < 64; m <<= 1) s += __shfl_xor(s, m);
    const float inv = 1.f / s;
    #pragma unroll
    for (int i = 0; i < 6; ++i) {
        int m = t + i * 64;
        if (m < N_) attn[b * N_ + m] = v[i] * inv;
    }
}

// ge[b,c] = sum_n attn[b,n] * h[b,n,c]
__global__ __launch_bounds__(256) void ge_kernel(
    const float* __restrict__ attn, const float* __restrict__ h, float* __restrict__ ge)
{
    __shared__ float a[N_];
    const int b = blockIdx.x;
    const int t = threadIdx.x;
    for (int m = t; m < N_; m += 256) a[m] = attn[b * N_ + m];
    __syncthreads();
    float acc = 0.f;
    const float* hp = h + (size_t)b * N_ * 256 + t;
    for (int m = 0; m < N_; ++m) acc += a[m] * hp[(size_t)m * 256];
    ge[b * 256 + t] = acc;
}

// Y[b,c] = (gelu?)(X[b,:] @ W[:,c] + bias[c]),  256x256 weights, 1 block per b
__global__ __launch_bounds__(256) void mlp_kernel(
    const float* __restrict__ X, const float* __restrict__ W,
    const float* __restrict__ bias, float* __restrict__ Y, int applyGelu)
{
    __shared__ float xs[256];
    const int b = blockIdx.x;
    const int t = threadIdx.x;
    xs[t] = X[b * 256 + t];
    __syncthreads();
    float acc = bias[t];
    for (int k = 0; k < 256; ++k) acc += xs[k] * W[k * 256 + t];
    if (applyGelu) acc = gelu_f(acc);
    Y[b * 256 + t] = acc;
}

// ---------------------------------------------------------------------------

extern "C" void kernel_launch(void* const* d_in, const int* in_sizes, int n_in,
                              void* d_out, int out_size, void* d_ws, size_t ws_size,
                              hipStream_t stream) {
    const float* mind  = (const float*)d_in[0];
    const float* roi   = (const float*)d_in[1];
    // d_in[2] group_prior, d_in[9..12] Wp1/bp1/Wp2/bp2: dead (mask all-true)
    const float* Wnp   = (const float*)d_in[3];
    const float* bnp   = (const float*)d_in[4];
    const float* Wrf   = (const float*)d_in[5];
    const float* brf   = (const float*)d_in[6];
    const float* ln_g  = (const float*)d_in[7];
    const float* ln_b  = (const float*)d_in[8];
    const float* gatW0 = (const float*)d_in[13];
    const float* gata0 = (const float*)d_in[14];
    const float* gatW1 = (const float*)d_in[15];
    const float* gata1 = (const float*)d_in[16];
    const float* gatW2 = (const float*)d_in[17];
    const float* gata2 = (const float*)d_in[18];
    const float* projW = (const float*)d_in[19];
    const float* projb = (const float*)d_in[20];
    const float* Wr1   = (const float*)d_in[21];
    const float* br1   = (const float*)d_in[22];
    const float* Wr2   = (const float*)d_in[23];
    const float* br2   = (const float*)d_in[24];

    const size_t SZ = (size_t)ROWS_ * D_;       // 5,898,240 floats
    float* ws    = (float*)d_ws;
    float* nf    = ws;
    float* h1    = nf + SZ;
    float* h2    = h1 + SZ;
    float* ht01  = h2 + SZ;
    float* ht2c  = ht01 + SZ;                   // 2880*2048 == SZ
    float* haggc = ht2c + SZ;
    float* ei_b  = haggc + SZ;                  // 23040*8
    float* ej_b  = ei_b + ROWS_ * H_;
    float* Wcomb = ej_b + ROWS_ * H_;           // 360*256
    float* bcomb = Wcomb + 360 * 256;           // 256
    float* norms = bcomb + 256;                 // 23040
    float* ge0   = norms + ROWS_;               // 16384
    float* ge1   = ge0 + B_ * D_;

    const size_t need = (size_t)(ge1 + B_ * D_ - ws) * sizeof(float);
    if (ws_size < need) return;  // insufficient scratch; avoid corruption

    float* out    = (float*)d_out;
    float* out_ge = out;
    float* out_h  = out + (size_t)B_ * D_;
    float* out_at = out_h + (size_t)ROWS_ * D_;

    const dim3 blk(256);

    // --- node feature fusion ---
    // Wcomb = Wnp @ Wrf_top  [360,256]
    gemm_dual<<<dim3(4, 6), blk, 0, stream>>>(
        Wnp, Wrf, 256, 256, 256,
        nullptr, nullptr, 0, 0, 0,
        nullptr, Wcomb, 360, 256, 256);
    biascomb_kernel<<<1, 256, 0, stream>>>(bnp, Wrf, brf, bcomb);
    // nf = mind@Wcomb + roi@Wrf_bot + bcomb
    gemm_dual<<<dim3(4, 360), blk, 0, stream>>>(
        mind, Wcomb, 360, 360, 256,
        roi, Wrf + 256 * 256, 256, 256, 256,
        bcomb, nf, ROWS_, 256, 256);
    ln_gelu_kernel<<<ROWS_, 64, 0, stream>>>(nf, ln_g, ln_b);

    // --- GAT layer 0 (dh=32) ---
    gemm_dual<<<dim3(4, 360), blk, 0, stream>>>(
        nf, gatW0, 256, 256, 256,
        nullptr, nullptr, 0, 0, 0,
        nullptr, ht01, ROWS_, 256, 256);
    eiej_kernel<32><<<ROWS_, 64, 0, stream>>>(ht01, gata0, ei_b, ej_b);
    gat_agg<32><<<dim3(12, B_ * H_), blk, 0, stream>>>(ht01, ei_b, ej_b, h1);

    // --- GAT layer 1 (dh=32) ---
    gemm_dual<<<dim3(4, 360), blk, 0, stream>>>(
        h1, gatW1, 256, 256, 256,
        nullptr, nullptr, 0, 0, 0,
        nullptr, ht01, ROWS_, 256, 256);
    eiej_kernel<32><<<ROWS_, 64, 0, stream>>>(ht01, gata1, ei_b, ej_b);
    gat_agg<32><<<dim3(12, B_ * H_), blk, 0, stream>>>(ht01, ei_b, ej_b, h2);

    // --- GAT layer 2 (dh=256, proj), chunked over batch (8 x 8) ---
    for (int bc = 0; bc < 8; ++bc) {
        const int CB = 8;                         // batches per chunk
        const int CR = CB * N_;                   // 2880 rows
        const float* h2c = h2 + (size_t)bc * CR * D_;
        gemm_dual<<<dim3(32, 45), blk, 0, stream>>>(
            h2c, gatW2, 256, 256, 2048,
            nullptr, nullptr, 0, 0, 0,
            nullptr, ht2c, CR, 2048, 2048);
        eiej_kernel<256><<<CR, 64, 0, stream>>>(ht2c, gata2, ei_b, ej_b);
        gat_agg<256><<<dim3(12, CB * H_), blk, 0, stream>>>(ht2c, ei_b, ej_b, haggc);
        gemm_dual<<<dim3(4, 45), blk, 0, stream>>>(
            haggc, projW, 2048, 2048, 256,
            nullptr, nullptr, 0, 0, 0,
            projb, out_h + (size_t)bc * CR * D_, CR, 256, 256);
    }

    // --- attention readout ---
    rownorm_kernel<<<ROWS_, 64, 0, stream>>>(out_h, norms);
    softmax_n_kernel<<<B_, 64, 0, stream>>>(norms, out_at);
    ge_kernel<<<B_, 256, 0, stream>>>(out_at, out_h, ge0);
    mlp_kernel<<<B_, 256, 0, stream>>>(ge0, Wr1, br1, ge1, 1);
    mlp_kernel<<<B_, 256, 0, stream>>>(ge1, Wr2, br2, out_ge, 0);
}

// Round 2
// 2784.571 us; speedup vs baseline: 1.9152x; 1.9152x over previous
//
#include <hip/hip_runtime.h>
#include <hip/hip_bf16.h>
#include <math.h>

// ---------------------------------------------------------------------------
// PriorEnhancedMindEncoder forward, fp32.
// Shapes: B=64, N=360, DH=256, H=8. dh(GAT0/1)=32, dh(GAT2)=256.
//
// Dead-code: adj_norm is strictly positive -> GAT mask all-true -> the whole
// group_prior/Wp1/Wp2/adjacency branch never influences the outputs. Skipped.
//
// Fusion 1: nf = mind@(Wnp@Wrf_top) + roi@Wrf_bot + (bnp@Wrf_top+brf), LN+GELU.
// Fusion 2 (R1): GAT layer 2 collapse. out = sum_h alpha_h @ (h2 @ G_h)
//   with G_h = gatW2_h @ projW_h  [256,256], and ei/ej via u_h = gatW2_h@a2_i,
//   v_h = gatW2_h@a2_j. Eliminates the [23040,2048] ht2/hagg tensors and the
//   two 24 GF GEMMs (incl. the 180-block K=2048 proj GEMM that was 56% of R0).
// ---------------------------------------------------------------------------

#define B_ 64
#define N_ 360
#define D_ 256
#define H_ 8
#define ROWS_ (B_ * N_)   // 23040

__device__ __forceinline__ float gelu_f(float x) {
    return 0.5f * x * (1.f + erff(x * 0.70710678118654752440f));
}

// ---------------------------------------------------------------------------
// Tiled fp32 GEMM: C[M,N] = A1[M,K1]@B1[K1,N] (+ A2[M,K2]@B2[K2,N]) + bias
// 64x64 tile, 256 threads, 4x4 microtile. Optional batching over blockIdx.z:
// pass-0 A/B and C get per-z element offsets sA/sB/sC (0 = no batching).
// ---------------------------------------------------------------------------
__global__ __launch_bounds__(256) void gemm_dual(
    const float* __restrict__ A1, const float* __restrict__ B1, int K1, int lda1, int ldb1,
    const float* __restrict__ A2, const float* __restrict__ B2, int K2, int lda2, int ldb2,
    const float* __restrict__ bias, float* __restrict__ C, int M, int N, int ldc,
    size_t sA, size_t sB, size_t sC)
{
    __shared__ float As[16][68];   // [k][m], padded
    __shared__ float Bs[16][64];   // [k][n]
    const int tid = threadIdx.x;
    const int z = blockIdx.z;
    const int bm = blockIdx.y * 64;
    const int bn = blockIdx.x * 64;
    const int tr = (tid >> 4) << 2;
    const int tc = (tid & 15) << 2;
    float acc[4][4] = {};

    for (int pass = 0; pass < 2; ++pass) {
        const float* Ab = pass ? A2 : A1;
        const float* Bb = pass ? B2 : B1;
        if (Ab == nullptr) continue;
        const float* A = Ab + (pass ? 0 : (size_t)z * sA);
        const float* Bm = Bb + (pass ? 0 : (size_t)z * sB);
        const int K = pass ? K2 : K1;
        const int lda = pass ? lda2 : lda1;
        const int ldb = pass ? ldb2 : ldb1;
        for (int k0 = 0; k0 < K; k0 += 16) {
            #pragma unroll
            for (int i = 0; i < 4; ++i) {
                int idx = tid + i * 256;
                int m = idx >> 4, k = idx & 15;
                int gr = bm + m, gk = k0 + k;
                float v = 0.f;
                if (gr < M && gk < K) v = A[(size_t)gr * lda + gk];
                As[k][m] = v;
            }
            #pragma unroll
            for (int i = 0; i < 4; ++i) {
                int idx = tid + i * 256;
                int k = idx >> 6, c = idx & 63;
                int gk = k0 + k, gc = bn + c;
                float v = 0.f;
                if (gk < K && gc < N) v = Bm[(size_t)gk * ldb + gc];
                Bs[k][c] = v;
            }
            __syncthreads();
            #pragma unroll
            for (int k = 0; k < 16; ++k) {
                float4 av = *(const float4*)&As[k][tr];
                float4 bv = *(const float4*)&Bs[k][tc];
                acc[0][0] += av.x * bv.x; acc[0][1] += av.x * bv.y;
                acc[0][2] += av.x * bv.z; acc[0][3] += av.x * bv.w;
                acc[1][0] += av.y * bv.x; acc[1][1] += av.y * bv.y;
                acc[1][2] += av.y * bv.z; acc[1][3] += av.y * bv.w;
                acc[2][0] += av.z * bv.x; acc[2][1] += av.z * bv.y;
                acc[2][2] += av.z * bv.z; acc[2][3] += av.z * bv.w;
                acc[3][0] += av.w * bv.x; acc[3][1] += av.w * bv.y;
                acc[3][2] += av.w * bv.z; acc[3][3] += av.w * bv.w;
            }
            __syncthreads();
        }
    }

    float* Cz = C + (size_t)z * sC;
    #pragma unroll
    for (int i = 0; i < 4; ++i) {
        int r = bm + tr + i;
        if (r >= M) break;
        #pragma unroll
        for (int j = 0; j < 4; ++j) {
            int c = bn + tc + j;
            if (c < N) {
                float v = acc[i][j];
                if (bias) v += bias[c];
                Cz[(size_t)r * ldc + c] = v;
            }
        }
    }
}

// bias_comb[c] = brf[c] + sum_k bnp[k] * Wrf[k, c]   (top half of Wrf)
__global__ __launch_bounds__(256) void biascomb_kernel(
    const float* __restrict__ bnp, const float* __restrict__ Wrf,
    const float* __restrict__ brf, float* __restrict__ bcomb)
{
    int c = threadIdx.x;
    float acc = brf[c];
    for (int k = 0; k < 256; ++k) acc += bnp[k] * Wrf[k * 256 + c];
    bcomb[c] = acc;
}

// u[h][i] = sum_j gatW2[i, h*256+j] * a2[h, j]; v[h][i] with a2[h, 256+j]
__global__ __launch_bounds__(256) void uv_kernel(
    const float* __restrict__ gatW2, const float* __restrict__ a2,
    float* __restrict__ u, float* __restrict__ v)
{
    const int h = blockIdx.x;
    const int i = threadIdx.x;
    const float* wrow = gatW2 + (size_t)i * 2048 + h * 256;
    const float* ai = a2 + h * 512;
    float su = 0.f, sv = 0.f;
    for (int j = 0; j < 256; ++j) {
        float w = wrow[j];
        su += w * ai[j];
        sv += w * ai[256 + j];
    }
    u[h * 256 + i] = su;
    v[h * 256 + i] = sv;
}

// LayerNorm(eps=1e-5) + exact GELU, in-place on rows of 256. 1 wave per row.
__global__ __launch_bounds__(64) void ln_gelu_kernel(
    float* __restrict__ x, const float* __restrict__ g, const float* __restrict__ b)
{
    const size_t row = blockIdx.x;
    const int t = threadIdx.x;
    float4 v = *(const float4*)&x[row * 256 + t * 4];
    float s = v.x + v.y + v.z + v.w;
    #pragma unroll
    for (int m = 1; m < 64; m <<= 1) s += __shfl_xor(s, m);
    float mean = s * (1.f / 256.f);
    float dx = v.x - mean, dy = v.y - mean, dz = v.z - mean, dw = v.w - mean;
    float q = dx * dx + dy * dy + dz * dz + dw * dw;
    #pragma unroll
    for (int m = 1; m < 64; m <<= 1) q += __shfl_xor(q, m);
    float rstd = 1.f / sqrtf(q * (1.f / 256.f) + 1e-5f);
    float4 gg = *(const float4*)&g[t * 4];
    float4 bb = *(const float4*)&b[t * 4];
    float4 r;
    r.x = gelu_f(dx * rstd * gg.x + bb.x);
    r.y = gelu_f(dy * rstd * gg.y + bb.y);
    r.z = gelu_f(dz * rstd * gg.z + bb.z);
    r.w = gelu_f(dw * rstd * gg.w + bb.w);
    *(float4*)&x[row * 256 + t * 4] = r;
}

// ei/ej for GAT0/1: per row: ei[h] = ht[row,h,:dh] . a[h,:dh]
template <int DH>
__global__ __launch_bounds__(64) void eiej_kernel(
    const float* __restrict__ ht, const float* __restrict__ a,
    float* __restrict__ ei, float* __restrict__ ej)
{
    const size_t row = blockIdx.x;
    const int t = threadIdx.x;
    constexpr int E = (H_ * DH) / 64;
    const int h = t >> 3;
    const int d0 = (t & 7) * E;
    const float* hp = ht + row * (H_ * DH) + h * DH + d0;
    const float* ap = a + h * 2 * DH + d0;
    float se = 0.f, sj = 0.f;
    #pragma unroll
    for (int i = 0; i < E; ++i) {
        float x = hp[i];
        se += x * ap[i];
        sj += x * ap[DH + i];
    }
    se += __shfl_xor(se, 1); sj += __shfl_xor(sj, 1);
    se += __shfl_xor(se, 2); sj += __shfl_xor(sj, 2);
    se += __shfl_xor(se, 4); sj += __shfl_xor(sj, 4);
    if ((t & 7) == 0) {
        ei[row * H_ + h] = se;
        ej[row * H_ + h] = sj;
    }
}

// ei2/ej2 for GAT2: per row: ei2[row,h] = h2[row,:] . u[h,:], ej2 with v.
__global__ __launch_bounds__(64) void eiej2_kernel(
    const float* __restrict__ h2, const float* __restrict__ u,
    const float* __restrict__ v, float* __restrict__ ei, float* __restrict__ ej)
{
    const size_t row = blockIdx.x;
    const int t = threadIdx.x;
    const int h = t >> 3;
    const int d0 = (t & 7) * 32;
    const float* hp = h2 + row * 256 + d0;
    const float* up = u + h * 256 + d0;
    const float* vp = v + h * 256 + d0;
    float se = 0.f, sj = 0.f;
    #pragma unroll
    for (int i = 0; i < 32; ++i) {
        float x = hp[i];
        se += x * up[i];
        sj += x * vp[i];
    }
    se += __shfl_xor(se, 1); sj += __shfl_xor(sj, 1);
    se += __shfl_xor(se, 2); sj += __shfl_xor(sj, 2);
    se += __shfl_xor(se, 4); sj += __shfl_xor(sj, 4);
    if ((t & 7) == 0) {
        ei[row * H_ + h] = se;
        ej[row * H_ + h] = sj;
    }
}

// GAT0/1 attention + aggregation for one (b,h), 32 query rows per block.
template <int DH>
__global__ __launch_bounds__(256) void gat_agg(
    const float* __restrict__ ht, const float* __restrict__ ei,
    const float* __restrict__ ej, float* __restrict__ out)
{
    constexpr int HD = H_ * DH;
    __shared__ float ejs[N_];
    __shared__ float eis[32];
    __shared__ float sc[32][N_];
    const int tid = threadIdx.x;
    const int bh = blockIdx.y;
    const int b = bh >> 3, h = bh & 7;
    const int n0 = blockIdx.x * 32;
    const int nrows = min(32, N_ - n0);

    for (int m = tid; m < N_; m += 256) ejs[m] = ej[(b * N_ + m) * H_ + h];
    if (tid < 32) eis[tid] = (tid < nrows) ? ei[(size_t)(b * N_ + n0 + tid) * H_ + h] : 0.f;
    __syncthreads();

    const int r = tid >> 3, sub = tid & 7;
    const float eir = eis[r];
    float rmax = -1e30f;
    for (int m = sub; m < N_; m += 8) {
        float s = eir + ejs[m];
        s = s > 0.f ? s : 0.2f * s;
        sc[r][m] = s;
        rmax = fmaxf(rmax, s);
    }
    rmax = fmaxf(rmax, __shfl_xor(rmax, 1));
    rmax = fmaxf(rmax, __shfl_xor(rmax, 2));
    rmax = fmaxf(rmax, __shfl_xor(rmax, 4));
    float rsum = 0.f;
    for (int m = sub; m < N_; m += 8) {
        float p = __expf(sc[r][m] - rmax);
        sc[r][m] = p;
        rsum += p;
    }
    rsum += __shfl_xor(rsum, 1);
    rsum += __shfl_xor(rsum, 2);
    rsum += __shfl_xor(rsum, 4);
    const float rinv = 1.f / rsum;
    for (int m = sub; m < N_; m += 8) sc[r][m] *= rinv;
    __syncthreads();

    // DH==32 path (GAT0/1)
    const int c = tid & (DH - 1);
    const int rg = tid >> 5;           // 8 groups x 4 rows
    const float* V = ht + (size_t)b * N_ * HD + h * DH + c;
    float acc[4] = {};
    for (int m = 0; m < N_; m += 4) {
        float v0 = V[(size_t)(m + 0) * HD];
        float v1 = V[(size_t)(m + 1) * HD];
        float v2 = V[(size_t)(m + 2) * HD];
        float v3 = V[(size_t)(m + 3) * HD];
        #pragma unroll
        for (int i = 0; i < 4; ++i) {
            float4 s4 = *(const float4*)&sc[rg * 4 + i][m];
            acc[i] += s4.x * v0 + s4.y * v1 + s4.z * v2 + s4.w * v3;
        }
    }
    #pragma unroll
    for (int i = 0; i < 4; ++i) {
        int rr = rg * 4 + i;
        if (rr < nrows)
            out[(size_t)(b * N_ + n0 + rr) * HD + h * DH + c] = acc[i];
    }
}

// GAT2 aggregate-accumulate for head h:
//   out[b, n0..n0+31, :] (+)= softmax_m(lrelu(ei2[n]+ej2[m])) @ Z[b]  (+ projb if h==0)
__global__ __launch_bounds__(256) void gat2_agg(
    const float* __restrict__ Z, const float* __restrict__ ei,
    const float* __restrict__ ej, const float* __restrict__ projb,
    float* __restrict__ out, int h)
{
    __shared__ float ejs[N_];
    __shared__ float eis[32];
    __shared__ float sc[32][N_];
    const int tid = threadIdx.x;
    const int b = blockIdx.y;
    const int n0 = blockIdx.x * 32;
    const int nrows = min(32, N_ - n0);

    for (int m = tid; m < N_; m += 256) ejs[m] = ej[(b * N_ + m) * H_ + h];
    if (tid < 32) eis[tid] = (tid < nrows) ? ei[(size_t)(b * N_ + n0 + tid) * H_ + h] : 0.f;
    __syncthreads();

    const int r = tid >> 3, sub = tid & 7;
    const float eir = eis[r];
    float rmax = -1e30f;
    for (int m = sub; m < N_; m += 8) {
        float s = eir + ejs[m];
        s = s > 0.f ? s : 0.2f * s;
        sc[r][m] = s;
        rmax = fmaxf(rmax, s);
    }
    rmax = fmaxf(rmax, __shfl_xor(rmax, 1));
    rmax = fmaxf(rmax, __shfl_xor(rmax, 2));
    rmax = fmaxf(rmax, __shfl_xor(rmax, 4));
    float rsum = 0.f;
    for (int m = sub; m < N_; m += 8) {
        float p = __expf(sc[r][m] - rmax);
        sc[r][m] = p;
        rsum += p;
    }
    rsum += __shfl_xor(rsum, 1);
    rsum += __shfl_xor(rsum, 2);
    rsum += __shfl_xor(rsum, 4);
    const float rinv = 1.f / rsum;
    for (int m = sub; m < N_; m += 8) sc[r][m] *= rinv;
    __syncthreads();

    const int c = tid;                       // 0..255
    const float* V = Z + (size_t)b * N_ * D_ + c;
    float acc[32];
    #pragma unroll
    for (int i = 0; i < 32; ++i) acc[i] = 0.f;
    for (int m = 0; m < N_; m += 4) {
        float v0 = V[(size_t)(m + 0) * D_];
        float v1 = V[(size_t)(m + 1) * D_];
        float v2 = V[(size_t)(m + 2) * D_];
        float v3 = V[(size_t)(m + 3) * D_];
        #pragma unroll
        for (int i = 0; i < 32; ++i) {
            float4 s4 = *(const float4*)&sc[i][m];
            acc[i] += s4.x * v0 + s4.y * v1 + s4.z * v2 + s4.w * v3;
        }
    }
    if (h == 0) {
        const float pb = projb[c];
        for (int i = 0; i < nrows; ++i)
            out[(size_t)(b * N_ + n0 + i) * D_ + c] = acc[i] + pb;
    } else {
        for (int i = 0; i < nrows; ++i) {
            size_t o = (size_t)(b * N_ + n0 + i) * D_ + c;
            out[o] += acc[i];
        }
    }
}

// row L2 norm of h rows (256 wide), 1 wave per row
__global__ __launch_bounds__(64) void rownorm_kernel(
    const float* __restrict__ h, float* __restrict__ nrm)
{
    const size_t row = blockIdx.x;
    const int t = threadIdx.x;
    float4 v = *(const float4*)&h[row * 256 + t * 4];
    float s = v.x * v.x + v.y * v.y + v.z * v.z + v.w * v.w;
    #pragma unroll
    for (int m = 1; m < 64; m <<= 1) s += __shfl_xor(s, m);
    if (t == 0) nrm[row] = sqrtf(s);
}

// softmax over N=360 per batch, 1 wave per batch
__global__ __launch_bounds__(64) void softmax_n_kernel(
    const float* __restrict__ nrm, float* __restrict__ attn)
{
    const int b = blockIdx.x;
    const int t = threadIdx.x;
    float v[6];
    float mx = -1e30f;
    #pragma unroll
    for (int i = 0; i < 6; ++i) {
        int m = t + i * 64;
        v[i] = (m < N_) ? nrm[b * N_ + m] : -1e30f;
        mx = fmaxf(mx, v[i]);
    }
    #pragma unroll
    for (int m = 1; m < 64; m <<= 1) mx = fmaxf(mx, __shfl_xor(mx, m));
    float s = 0.f;
    #pragma unroll
    for (int i = 0; i < 6; ++i) {
        int m = t + i * 64;
        float p = (m < N_) ? __expf(v[i] - mx) : 0.f;
        v[i] = p;
        s += p;
    }
    #pragma unroll
    for (int m = 1; m < 64; m <<= 1) s += __shfl_xor(s, m);
    const float inv = 1.f / s;
    #pragma unroll
    for (int i = 0; i < 6; ++i) {
        int m = t + i * 64;
        if (m < N_) attn[b * N_ + m] = v[i] * inv;
    }
}

// ge[b,c] = sum_n attn[b,n] * h[b,n,c]
__global__ __launch_bounds__(256) void ge_kernel(
    const float* __restrict__ attn, const float* __restrict__ h, float* __restrict__ ge)
{
    __shared__ float a[N_];
    const int b = blockIdx.x;
    const int t = threadIdx.x;
    for (int m = t; m < N_; m += 256) a[m] = attn[b * N_ + m];
    __syncthreads();
    float acc = 0.f;
    const float* hp = h + (size_t)b * N_ * 256 + t;
    for (int m = 0; m < N_; ++m) acc += a[m] * hp[(size_t)m * 256];
    ge[b * 256 + t] = acc;
}

// Y[b,c] = (gelu?)(X[b,:] @ W[:,c] + bias[c]),  256x256 weights, 1 block per b
__global__ __launch_bounds__(256) void mlp_kernel(
    const float* __restrict__ X, const float* __restrict__ W,
    const float* __restrict__ bias, float* __restrict__ Y, int applyGelu)
{
    __shared__ float xs[256];
    const int b = blockIdx.x;
    const int t = threadIdx.x;
    xs[t] = X[b * 256 + t];
    __syncthreads();
    float acc = bias[t];
    for (int k = 0; k < 256; ++k) acc += xs[k] * W[k * 256 + t];
    if (applyGelu) acc = gelu_f(acc);
    Y[b * 256 + t] = acc;
}

// ---------------------------------------------------------------------------

extern "C" void kernel_launch(void* const* d_in, const int* in_sizes, int n_in,
                              void* d_out, int out_size, void* d_ws, size_t ws_size,
                              hipStream_t stream) {
    const float* mind  = (const float*)d_in[0];
    const float* roi   = (const float*)d_in[1];
    // d_in[2] group_prior, d_in[9..12] Wp1/bp1/Wp2/bp2: dead (mask all-true)
    const float* Wnp   = (const float*)d_in[3];
    const float* bnp   = (const float*)d_in[4];
    const float* Wrf   = (const float*)d_in[5];
    const float* brf   = (const float*)d_in[6];
    const float* ln_g  = (const float*)d_in[7];
    const float* ln_b  = (const float*)d_in[8];
    const float* gatW0 = (const float*)d_in[13];
    const float* gata0 = (const float*)d_in[14];
    const float* gatW1 = (const float*)d_in[15];
    const float* gata1 = (const float*)d_in[16];
    const float* gatW2 = (const float*)d_in[17];
    const float* gata2 = (const float*)d_in[18];
    const float* projW = (const float*)d_in[19];
    const float* projb = (const float*)d_in[20];
    const float* Wr1   = (const float*)d_in[21];
    const float* br1   = (const float*)d_in[22];
    const float* Wr2   = (const float*)d_in[23];
    const float* br2   = (const float*)d_in[24];

    const size_t SZ = (size_t)ROWS_ * D_;       // 5,898,240 floats
    float* ws    = (float*)d_ws;
    float* nf    = ws;                          // [23040,256]
    float* h1    = nf + SZ;
    float* h2    = h1 + SZ;
    float* ht01  = h2 + SZ;                     // GAT0/1 projections
    float* Z     = ht01 + SZ;                   // per-head h2 @ G_h
    float* ei_b  = Z + SZ;                      // 23040*8
    float* ej_b  = ei_b + ROWS_ * H_;
    float* Wcomb = ej_b + ROWS_ * H_;           // 360*256
    float* bcomb = Wcomb + 360 * 256;           // 256
    float* Gbuf  = bcomb + 256;                 // 8*256*256
    float* uvec  = Gbuf + 8 * 256 * 256;        // 8*256
    float* vvec  = uvec + 8 * 256;              // 8*256
    float* norms = vvec + 8 * 256;              // 23040
    float* ge0   = norms + ROWS_;               // 16384
    float* ge1   = ge0 + B_ * D_;

    const size_t need = (size_t)(ge1 + B_ * D_ - ws) * sizeof(float);
    if (ws_size < need) return;  // insufficient scratch; avoid corruption

    float* out    = (float*)d_out;
    float* out_ge = out;
    float* out_h  = out + (size_t)B_ * D_;
    float* out_at = out_h + (size_t)ROWS_ * D_;

    const dim3 blk(256);

    // --- node feature fusion ---
    gemm_dual<<<dim3(4, 6), blk, 0, stream>>>(
        Wnp, Wrf, 256, 256, 256,
        nullptr, nullptr, 0, 0, 0,
        nullptr, Wcomb, 360, 256, 256, 0, 0, 0);
    biascomb_kernel<<<1, 256, 0, stream>>>(bnp, Wrf, brf, bcomb);
    gemm_dual<<<dim3(4, 360), blk, 0, stream>>>(
        mind, Wcomb, 360, 360, 256,
        roi, Wrf + 256 * 256, 256, 256, 256,
        bcomb, nf, ROWS_, 256, 256, 0, 0, 0);
    ln_gelu_kernel<<<ROWS_, 64, 0, stream>>>(nf, ln_g, ln_b);

    // --- GAT layer 0 (dh=32) ---
    gemm_dual<<<dim3(4, 360), blk, 0, stream>>>(
        nf, gatW0, 256, 256, 256,
        nullptr, nullptr, 0, 0, 0,
        nullptr, ht01, ROWS_, 256, 256, 0, 0, 0);
    eiej_kernel<32><<<ROWS_, 64, 0, stream>>>(ht01, gata0, ei_b, ej_b);
    gat_agg<32><<<dim3(12, B_ * H_), blk, 0, stream>>>(ht01, ei_b, ej_b, h1);

    // --- GAT layer 1 (dh=32) ---
    gemm_dual<<<dim3(4, 360), blk, 0, stream>>>(
        h1, gatW1, 256, 256, 256,
        nullptr, nullptr, 0, 0, 0,
        nullptr, ht01, ROWS_, 256, 256, 0, 0, 0);
    eiej_kernel<32><<<ROWS_, 64, 0, stream>>>(ht01, gata1, ei_b, ej_b);
    gat_agg<32><<<dim3(12, B_ * H_), blk, 0, stream>>>(ht01, ei_b, ej_b, h2);

    // --- GAT layer 2 (collapsed): G_h = gatW2_h @ projW_h; out = sum_h a_h@(h2@G_h)
    gemm_dual<<<dim3(4, 4, 8), blk, 0, stream>>>(
        gatW2, projW, 256, 2048, 256,
        nullptr, nullptr, 0, 0, 0,
        nullptr, Gbuf, 256, 256, 256,
        /*sA=*/256, /*sB=*/(size_t)256 * 256, /*sC=*/(size_t)256 * 256);
    uv_kernel<<<8, 256, 0, stream>>>(gatW2, gata2, uvec, vvec);
    eiej2_kernel<<<ROWS_, 64, 0, stream>>>(h2, uvec, vvec, ei_b, ej_b);

    for (int h = 0; h < H_; ++h) {
        gemm_dual<<<dim3(4, 360), blk, 0, stream>>>(
            h2, Gbuf + (size_t)h * 256 * 256, 256, 256, 256,
            nullptr, nullptr, 0, 0, 0,
            nullptr, Z, ROWS_, 256, 256, 0, 0, 0);
        gat2_agg<<<dim3(12, B_), blk, 0, stream>>>(
            Z, ei_b, ej_b, projb, out_h, h);
    }

    // --- attention readout ---
    rownorm_kernel<<<ROWS_, 64, 0, stream>>>(out_h, norms);
    softmax_n_kernel<<<B_, 64, 0, stream>>>(norms, out_at);
    ge_kernel<<<B_, 256, 0, stream>>>(out_at, out_h, ge0);
    mlp_kernel<<<B_, 256, 0, stream>>>(ge0, Wr1, br1, ge1, 1);
    mlp_kernel<<<B_, 256, 0, stream>>>(ge1, Wr2, br2, out_ge, 0);
}

// Round 4
// 2653.158 us; speedup vs baseline: 2.0101x; 1.0495x over previous
//
#include <hip/hip_runtime.h>
#include <hip/hip_bf16.h>
#include <math.h>

// ---------------------------------------------------------------------------
// PriorEnhancedMindEncoder forward, fp32.
// Shapes: B=64, N=360, DH=256, H=8. dh(GAT0/1)=32, dh(GAT2)=256.
//
// Dead-code: adj_norm strictly positive -> GAT mask all-true -> group_prior/
// Wp1/Wp2 branch never influences outputs. Skipped.
// Fusion 1: nf = mind@(Wnp@Wrf_top) + roi@Wrf_bot + (bnp@Wrf_top+brf), LN+GELU.
// Fusion 2: GAT2 collapse: out = sum_h alpha_h @ (h2 @ G_h), G_h = gatW2_h@projW_h.
// R3: gemm rewritten: 128x64 tile, 8x4 microtile, K-step 32, double-buffered
//     LDS, 1 barrier/step (R2 GEMMs were latency-bound: VALU 27%, 12 TF).
//     (Resubmitted unchanged after R3 GPUAcquisitionTimeout.)
// ---------------------------------------------------------------------------

#define B_ 64
#define N_ 360
#define D_ 256
#define H_ 8
#define ROWS_ (B_ * N_)   // 23040

__device__ __forceinline__ float gelu_f(float x) {
    return 0.5f * x * (1.f + erff(x * 0.70710678118654752440f));
}

// ---------------------------------------------------------------------------
// Tiled fp32 GEMM: C[M,N] = A1[M,K1]@B1[K1,N] (+ A2[M,K2]@B2[K2,N]) + bias
// 128x64 tile, 256 threads, 8x4 microtile, K-step 32, double-buffered LDS.
// Optional z-batching: pass-0 A/B and C shifted by z*sA / z*sB / z*sC elems.
// ---------------------------------------------------------------------------
__global__ __launch_bounds__(256) void gemm_tiled(
    const float* __restrict__ A1, const float* __restrict__ B1, int K1, int lda1, int ldb1,
    const float* __restrict__ A2, const float* __restrict__ B2, int K2, int lda2, int ldb2,
    const float* __restrict__ bias, float* __restrict__ C, int M, int N, int ldc,
    size_t sA, size_t sB, size_t sC)
{
    __shared__ float As[2][32][132];   // [buf][k][row], pad 132 (4-way wr, clean rd)
    __shared__ float Bs[2][32][64];    // [buf][k][col]
    const int tid = threadIdx.x;
    const int z = blockIdx.z;
    const int bm = blockIdx.y * 128;
    const int bn = blockIdx.x * 64;
    const int tr = (tid >> 4) * 8;     // 0..120
    const int tc = (tid & 15) * 4;     // 0..60
    const int lar = tid >> 3;          // A-load row base (0..31), +j*32
    const int lak = (tid & 7) * 4;     // A-load k
    const int lbk = tid >> 4;          // B-load k base (0..15), +j*16
    const int lbc = (tid & 15) * 4;    // B-load col

    float acc[8][4] = {};
    float4 rA[4], rB[2];

    for (int pass = 0; pass < 2; ++pass) {
        const float* Ab = pass ? A2 : A1;
        const float* Bb = pass ? B2 : B1;
        if (Ab == nullptr) continue;
        const float* A  = Ab + (pass ? (size_t)0 : (size_t)z * sA);
        const float* Bm = Bb + (pass ? (size_t)0 : (size_t)z * sB);
        const int K   = pass ? K2 : K1;
        const int lda = pass ? lda2 : lda1;
        const int ldb = pass ? ldb2 : ldb1;
        const int S = (K + 31) >> 5;

        auto loadA = [&](int s) {
            const int k0 = s << 5;
            #pragma unroll
            for (int j = 0; j < 4; ++j) {
                const int gr = bm + lar + j * 32;
                const int gk = k0 + lak;
                float4 v; v.x = v.y = v.z = v.w = 0.f;
                if (gr < M) {
                    if (gk + 3 < K) {
                        v = *(const float4*)&A[(size_t)gr * lda + gk];
                    } else {
                        float t0 = 0.f, t1 = 0.f, t2 = 0.f, t3 = 0.f;
                        if (gk + 0 < K) t0 = A[(size_t)gr * lda + gk + 0];
                        if (gk + 1 < K) t1 = A[(size_t)gr * lda + gk + 1];
                        if (gk + 2 < K) t2 = A[(size_t)gr * lda + gk + 2];
                        if (gk + 3 < K) t3 = A[(size_t)gr * lda + gk + 3];
                        v.x = t0; v.y = t1; v.z = t2; v.w = t3;
                    }
                }
                rA[j] = v;
            }
        };
        auto loadB = [&](int s) {
            const int k0 = s << 5;
            #pragma unroll
            for (int j = 0; j < 2; ++j) {
                const int gk = k0 + lbk + j * 16;
                float4 v; v.x = v.y = v.z = v.w = 0.f;
                if (gk < K) v = *(const float4*)&Bm[(size_t)gk * ldb + bn + lbc];
                rB[j] = v;
            }
        };
        auto storeA = [&](int buf) {
            #pragma unroll
            for (int j = 0; j < 4; ++j) {
                const int row = lar + j * 32;
                As[buf][lak + 0][row] = rA[j].x;
                As[buf][lak + 1][row] = rA[j].y;
                As[buf][lak + 2][row] = rA[j].z;
                As[buf][lak + 3][row] = rA[j].w;
            }
        };
        auto storeB = [&](int buf) {
            #pragma unroll
            for (int j = 0; j < 2; ++j)
                *(float4*)&Bs[buf][lbk + j * 16][lbc] = rB[j];
        };

        loadA(0); loadB(0);
        storeA(0); storeB(0);
        __syncthreads();
        for (int s = 0; s < S; ++s) {
            const int cur = s & 1;
            if (s + 1 < S) { loadA(s + 1); loadB(s + 1); }   // async, hides under compute
            #pragma unroll
            for (int k = 0; k < 32; ++k) {
                const float4 a0 = *(const float4*)&As[cur][k][tr];
                const float4 a1 = *(const float4*)&As[cur][k][tr + 4];
                const float4 bv = *(const float4*)&Bs[cur][k][tc];
                const float av[8] = {a0.x, a0.y, a0.z, a0.w, a1.x, a1.y, a1.z, a1.w};
                const float bb[4] = {bv.x, bv.y, bv.z, bv.w};
                #pragma unroll
                for (int i = 0; i < 8; ++i)
                    #pragma unroll
                    for (int j = 0; j < 4; ++j)
                        acc[i][j] += av[i] * bb[j];
            }
            if (s + 1 < S) { storeA(cur ^ 1); storeB(cur ^ 1); }
            __syncthreads();
        }
    }

    float4 bz; bz.x = bz.y = bz.z = bz.w = 0.f;
    if (bias) bz = *(const float4*)&bias[bn + tc];
    float* Cz = C + (size_t)z * sC;
    #pragma unroll
    for (int i = 0; i < 8; ++i) {
        const int r = bm + tr + i;
        if (r < M) {
            float4 o;
            o.x = acc[i][0] + bz.x;
            o.y = acc[i][1] + bz.y;
            o.z = acc[i][2] + bz.z;
            o.w = acc[i][3] + bz.w;
            *(float4*)&Cz[(size_t)r * ldc + bn + tc] = o;
        }
    }
}

// bias_comb[c] = brf[c] + sum_k bnp[k] * Wrf[k, c]   (top half of Wrf)
__global__ __launch_bounds__(256) void biascomb_kernel(
    const float* __restrict__ bnp, const float* __restrict__ Wrf,
    const float* __restrict__ brf, float* __restrict__ bcomb)
{
    int c = threadIdx.x;
    float acc = brf[c];
    for (int k = 0; k < 256; ++k) acc += bnp[k] * Wrf[k * 256 + c];
    bcomb[c] = acc;
}

// u[h][i] = sum_j gatW2[i, h*256+j] * a2[h, j]; v[h][i] with a2[h, 256+j]
__global__ __launch_bounds__(256) void uv_kernel(
    const float* __restrict__ gatW2, const float* __restrict__ a2,
    float* __restrict__ u, float* __restrict__ v)
{
    const int h = blockIdx.x;
    const int i = threadIdx.x;
    const float* wrow = gatW2 + (size_t)i * 2048 + h * 256;
    const float* ai = a2 + h * 512;
    float su = 0.f, sv = 0.f;
    for (int j = 0; j < 256; ++j) {
        float w = wrow[j];
        su += w * ai[j];
        sv += w * ai[256 + j];
    }
    u[h * 256 + i] = su;
    v[h * 256 + i] = sv;
}

// LayerNorm(eps=1e-5) + exact GELU, in-place on rows of 256. 1 wave per row.
__global__ __launch_bounds__(64) void ln_gelu_kernel(
    float* __restrict__ x, const float* __restrict__ g, const float* __restrict__ b)
{
    const size_t row = blockIdx.x;
    const int t = threadIdx.x;
    float4 v = *(const float4*)&x[row * 256 + t * 4];
    float s = v.x + v.y + v.z + v.w;
    #pragma unroll
    for (int m = 1; m < 64; m <<= 1) s += __shfl_xor(s, m);
    float mean = s * (1.f / 256.f);
    float dx = v.x - mean, dy = v.y - mean, dz = v.z - mean, dw = v.w - mean;
    float q = dx * dx + dy * dy + dz * dz + dw * dw;
    #pragma unroll
    for (int m = 1; m < 64; m <<= 1) q += __shfl_xor(q, m);
    float rstd = 1.f / sqrtf(q * (1.f / 256.f) + 1e-5f);
    float4 gg = *(const float4*)&g[t * 4];
    float4 bb = *(const float4*)&b[t * 4];
    float4 r;
    r.x = gelu_f(dx * rstd * gg.x + bb.x);
    r.y = gelu_f(dy * rstd * gg.y + bb.y);
    r.z = gelu_f(dz * rstd * gg.z + bb.z);
    r.w = gelu_f(dw * rstd * gg.w + bb.w);
    *(float4*)&x[row * 256 + t * 4] = r;
}

// ei/ej for GAT0/1: per row: ei[h] = ht[row,h,:dh] . a[h,:dh]
template <int DH>
__global__ __launch_bounds__(64) void eiej_kernel(
    const float* __restrict__ ht, const float* __restrict__ a,
    float* __restrict__ ei, float* __restrict__ ej)
{
    const size_t row = blockIdx.x;
    const int t = threadIdx.x;
    constexpr int E = (H_ * DH) / 64;   // floats per thread (4 for DH=32)
    const int h = t >> 3;
    const int d0 = (t & 7) * E;
    const float* hp = ht + row * (H_ * DH) + h * DH + d0;
    const float* ap = a + h * 2 * DH + d0;
    float se = 0.f, sj = 0.f;
    #pragma unroll
    for (int i = 0; i < E; i += 4) {
        float4 x = *(const float4*)&hp[i];
        float4 u = *(const float4*)&ap[i];
        float4 w = *(const float4*)&ap[DH + i];
        se += x.x * u.x + x.y * u.y + x.z * u.z + x.w * u.w;
        sj += x.x * w.x + x.y * w.y + x.z * w.z + x.w * w.w;
    }
    se += __shfl_xor(se, 1); sj += __shfl_xor(sj, 1);
    se += __shfl_xor(se, 2); sj += __shfl_xor(sj, 2);
    se += __shfl_xor(se, 4); sj += __shfl_xor(sj, 4);
    if ((t & 7) == 0) {
        ei[row * H_ + h] = se;
        ej[row * H_ + h] = sj;
    }
}

// ei2/ej2 for GAT2: per row: ei2[row,h] = h2[row,:] . u[h,:], ej2 with v.
__global__ __launch_bounds__(64) void eiej2_kernel(
    const float* __restrict__ h2, const float* __restrict__ u,
    const float* __restrict__ v, float* __restrict__ ei, float* __restrict__ ej)
{
    const size_t row = blockIdx.x;
    const int t = threadIdx.x;
    const int h = t >> 3;
    const int d0 = (t & 7) * 32;
    const float* hp = h2 + row * 256 + d0;
    const float* up = u + h * 256 + d0;
    const float* vp = v + h * 256 + d0;
    float se = 0.f, sj = 0.f;
    #pragma unroll
    for (int i = 0; i < 32; i += 4) {
        float4 x = *(const float4*)&hp[i];
        float4 uu = *(const float4*)&up[i];
        float4 vv = *(const float4*)&vp[i];
        se += x.x * uu.x + x.y * uu.y + x.z * uu.z + x.w * uu.w;
        sj += x.x * vv.x + x.y * vv.y + x.z * vv.z + x.w * vv.w;
    }
    se += __shfl_xor(se, 1); sj += __shfl_xor(sj, 1);
    se += __shfl_xor(se, 2); sj += __shfl_xor(sj, 2);
    se += __shfl_xor(se, 4); sj += __shfl_xor(sj, 4);
    if ((t & 7) == 0) {
        ei[row * H_ + h] = se;
        ej[row * H_ + h] = sj;
    }
}

// GAT0/1 attention + aggregation for one (b,h), 32 query rows per block.
template <int DH>
__global__ __launch_bounds__(256) void gat_agg(
    const float* __restrict__ ht, const float* __restrict__ ei,
    const float* __restrict__ ej, float* __restrict__ out)
{
    constexpr int HD = H_ * DH;
    __shared__ float ejs[N_];
    __shared__ float eis[32];
    __shared__ float sc[32][N_];
    const int tid = threadIdx.x;
    const int bh = blockIdx.y;
    const int b = bh >> 3, h = bh & 7;
    const int n0 = blockIdx.x * 32;
    const int nrows = min(32, N_ - n0);

    for (int m = tid; m < N_; m += 256) ejs[m] = ej[(b * N_ + m) * H_ + h];
    if (tid < 32) eis[tid] = (tid < nrows) ? ei[(size_t)(b * N_ + n0 + tid) * H_ + h] : 0.f;
    __syncthreads();

    const int r = tid >> 3, sub = tid & 7;
    const float eir = eis[r];
    float rmax = -1e30f;
    for (int m = sub; m < N_; m += 8) {
        float s = eir + ejs[m];
        s = s > 0.f ? s : 0.2f * s;
        sc[r][m] = s;
        rmax = fmaxf(rmax, s);
    }
    rmax = fmaxf(rmax, __shfl_xor(rmax, 1));
    rmax = fmaxf(rmax, __shfl_xor(rmax, 2));
    rmax = fmaxf(rmax, __shfl_xor(rmax, 4));
    float rsum = 0.f;
    for (int m = sub; m < N_; m += 8) {
        float p = __expf(sc[r][m] - rmax);
        sc[r][m] = p;
        rsum += p;
    }
    rsum += __shfl_xor(rsum, 1);
    rsum += __shfl_xor(rsum, 2);
    rsum += __shfl_xor(rsum, 4);
    const float rinv = 1.f / rsum;
    for (int m = sub; m < N_; m += 8) sc[r][m] *= rinv;
    __syncthreads();

    // DH==32 path (GAT0/1)
    const int c = tid & (DH - 1);
    const int rg = tid >> 5;           // 8 groups x 4 rows
    const float* V = ht + (size_t)b * N_ * HD + h * DH + c;
    float acc[4] = {};
    for (int m = 0; m < N_; m += 4) {
        float v0 = V[(size_t)(m + 0) * HD];
        float v1 = V[(size_t)(m + 1) * HD];
        float v2 = V[(size_t)(m + 2) * HD];
        float v3 = V[(size_t)(m + 3) * HD];
        #pragma unroll
        for (int i = 0; i < 4; ++i) {
            float4 s4 = *(const float4*)&sc[rg * 4 + i][m];
            acc[i] += s4.x * v0 + s4.y * v1 + s4.z * v2 + s4.w * v3;
        }
    }
    #pragma unroll
    for (int i = 0; i < 4; ++i) {
        int rr = rg * 4 + i;
        if (rr < nrows)
            out[(size_t)(b * N_ + n0 + rr) * HD + h * DH + c] = acc[i];
    }
}

// GAT2 aggregate-accumulate for head h:
//   out[b, n0..n0+31, :] (+)= softmax_m(lrelu(ei2[n]+ej2[m])) @ Z[b]  (+ projb if h==0)
__global__ __launch_bounds__(256) void gat2_agg(
    const float* __restrict__ Z, const float* __restrict__ ei,
    const float* __restrict__ ej, const float* __restrict__ projb,
    float* __restrict__ out, int h)
{
    __shared__ float ejs[N_];
    __shared__ float eis[32];
    __shared__ float sc[32][N_];
    const int tid = threadIdx.x;
    const int b = blockIdx.y;
    const int n0 = blockIdx.x * 32;
    const int nrows = min(32, N_ - n0);

    for (int m = tid; m < N_; m += 256) ejs[m] = ej[(b * N_ + m) * H_ + h];
    if (tid < 32) eis[tid] = (tid < nrows) ? ei[(size_t)(b * N_ + n0 + tid) * H_ + h] : 0.f;
    __syncthreads();

    const int r = tid >> 3, sub = tid & 7;
    const float eir = eis[r];
    float rmax = -1e30f;
    for (int m = sub; m < N_; m += 8) {
        float s = eir + ejs[m];
        s = s > 0.f ? s : 0.2f * s;
        sc[r][m] = s;
        rmax = fmaxf(rmax, s);
    }
    rmax = fmaxf(rmax, __shfl_xor(rmax, 1));
    rmax = fmaxf(rmax, __shfl_xor(rmax, 2));
    rmax = fmaxf(rmax, __shfl_xor(rmax, 4));
    float rsum = 0.f;
    for (int m = sub; m < N_; m += 8) {
        float p = __expf(sc[r][m] - rmax);
        sc[r][m] = p;
        rsum += p;
    }
    rsum += __shfl_xor(rsum, 1);
    rsum += __shfl_xor(rsum, 2);
    rsum += __shfl_xor(rsum, 4);
    const float rinv = 1.f / rsum;
    for (int m = sub; m < N_; m += 8) sc[r][m] *= rinv;
    __syncthreads();

    const int c = tid;                       // 0..255
    const float* V = Z + (size_t)b * N_ * D_ + c;
    float acc[32];
    #pragma unroll
    for (int i = 0; i < 32; ++i) acc[i] = 0.f;
    for (int m = 0; m < N_; m += 4) {
        float v0 = V[(size_t)(m + 0) * D_];
        float v1 = V[(size_t)(m + 1) * D_];
        float v2 = V[(size_t)(m + 2) * D_];
        float v3 = V[(size_t)(m + 3) * D_];
        #pragma unroll
        for (int i = 0; i < 32; ++i) {
            float4 s4 = *(const float4*)&sc[i][m];
            acc[i] += s4.x * v0 + s4.y * v1 + s4.z * v2 + s4.w * v3;
        }
    }
    if (h == 0) {
        const float pb = projb[c];
        for (int i = 0; i < nrows; ++i)
            out[(size_t)(b * N_ + n0 + i) * D_ + c] = acc[i] + pb;
    } else {
        for (int i = 0; i < nrows; ++i) {
            size_t o = (size_t)(b * N_ + n0 + i) * D_ + c;
            out[o] += acc[i];
        }
    }
}

// row L2 norm of h rows (256 wide), 1 wave per row
__global__ __launch_bounds__(64) void rownorm_kernel(
    const float* __restrict__ h, float* __restrict__ nrm)
{
    const size_t row = blockIdx.x;
    const int t = threadIdx.x;
    float4 v = *(const float4*)&h[row * 256 + t * 4];
    float s = v.x * v.x + v.y * v.y + v.z * v.z + v.w * v.w;
    #pragma unroll
    for (int m = 1; m < 64; m <<= 1) s += __shfl_xor(s, m);
    if (t == 0) nrm[row] = sqrtf(s);
}

// softmax over N=360 per batch, 1 wave per batch
__global__ __launch_bounds__(64) void softmax_n_kernel(
    const float* __restrict__ nrm, float* __restrict__ attn)
{
    const int b = blockIdx.x;
    const int t = threadIdx.x;
    float v[6];
    float mx = -1e30f;
    #pragma unroll
    for (int i = 0; i < 6; ++i) {
        int m = t + i * 64;
        v[i] = (m < N_) ? nrm[b * N_ + m] : -1e30f;
        mx = fmaxf(mx, v[i]);
    }
    #pragma unroll
    for (int m = 1; m < 64; m <<= 1) mx = fmaxf(mx, __shfl_xor(mx, m));
    float s = 0.f;
    #pragma unroll
    for (int i = 0; i < 6; ++i) {
        int m = t + i * 64;
        float p = (m < N_) ? __expf(v[i] - mx) : 0.f;
        v[i] = p;
        s += p;
    }
    #pragma unroll
    for (int m = 1; m < 64; m <<= 1) s += __shfl_xor(s, m);
    const float inv = 1.f / s;
    #pragma unroll
    for (int i = 0; i < 6; ++i) {
        int m = t + i * 64;
        if (m < N_) attn[b * N_ + m] = v[i] * inv;
    }
}

// ge[b,c] = sum_n attn[b,n] * h[b,n,c]
__global__ __launch_bounds__(256) void ge_kernel(
    const float* __restrict__ attn, const float* __restrict__ h, float* __restrict__ ge)
{
    __shared__ float a[N_];
    const int b = blockIdx.x;
    const int t = threadIdx.x;
    for (int m = t; m < N_; m += 256) a[m] = attn[b * N_ + m];
    __syncthreads();
    float acc = 0.f;
    const float* hp = h + (size_t)b * N_ * 256 + t;
    for (int m = 0; m < N_; ++m) acc += a[m] * hp[(size_t)m * 256];
    ge[b * 256 + t] = acc;
}

// Y[b,c] = (gelu?)(X[b,:] @ W[:,c] + bias[c]),  256x256 weights, 1 block per b
__global__ __launch_bounds__(256) void mlp_kernel(
    const float* __restrict__ X, const float* __restrict__ W,
    const float* __restrict__ bias, float* __restrict__ Y, int applyGelu)
{
    __shared__ float xs[256];
    const int b = blockIdx.x;
    const int t = threadIdx.x;
    xs[t] = X[b * 256 + t];
    __syncthreads();
    float acc = bias[t];
    for (int k = 0; k < 256; ++k) acc += xs[k] * W[k * 256 + t];
    if (applyGelu) acc = gelu_f(acc);
    Y[b * 256 + t] = acc;
}

// ---------------------------------------------------------------------------

extern "C" void kernel_launch(void* const* d_in, const int* in_sizes, int n_in,
                              void* d_out, int out_size, void* d_ws, size_t ws_size,
                              hipStream_t stream) {
    const float* mind  = (const float*)d_in[0];
    const float* roi   = (const float*)d_in[1];
    // d_in[2] group_prior, d_in[9..12] Wp1/bp1/Wp2/bp2: dead (mask all-true)
    const float* Wnp   = (const float*)d_in[3];
    const float* bnp   = (const float*)d_in[4];
    const float* Wrf   = (const float*)d_in[5];
    const float* brf   = (const float*)d_in[6];
    const float* ln_g  = (const float*)d_in[7];
    const float* ln_b  = (const float*)d_in[8];
    const float* gatW0 = (const float*)d_in[13];
    const float* gata0 = (const float*)d_in[14];
    const float* gatW1 = (const float*)d_in[15];
    const float* gata1 = (const float*)d_in[16];
    const float* gatW2 = (const float*)d_in[17];
    const float* gata2 = (const float*)d_in[18];
    const float* projW = (const float*)d_in[19];
    const float* projb = (const float*)d_in[20];
    const float* Wr1   = (const float*)d_in[21];
    const float* br1   = (const float*)d_in[22];
    const float* Wr2   = (const float*)d_in[23];
    const float* br2   = (const float*)d_in[24];

    const size_t SZ = (size_t)ROWS_ * D_;       // 5,898,240 floats
    float* ws    = (float*)d_ws;
    float* nf    = ws;                          // [23040,256]
    float* h1    = nf + SZ;
    float* h2    = h1 + SZ;
    float* ht01  = h2 + SZ;                     // GAT0/1 projections
    float* Z     = ht01 + SZ;                   // per-head h2 @ G_h
    float* ei_b  = Z + SZ;                      // 23040*8
    float* ej_b  = ei_b + ROWS_ * H_;
    float* Wcomb = ej_b + ROWS_ * H_;           // 360*256
    float* bcomb = Wcomb + 360 * 256;           // 256
    float* Gbuf  = bcomb + 256;                 // 8*256*256
    float* uvec  = Gbuf + 8 * 256 * 256;        // 8*256
    float* vvec  = uvec + 8 * 256;              // 8*256
    float* norms = vvec + 8 * 256;              // 23040
    float* ge0   = norms + ROWS_;               // 16384
    float* ge1   = ge0 + B_ * D_;

    const size_t need = (size_t)(ge1 + B_ * D_ - ws) * sizeof(float);
    if (ws_size < need) return;  // insufficient scratch; avoid corruption

    float* out    = (float*)d_out;
    float* out_ge = out;
    float* out_h  = out + (size_t)B_ * D_;
    float* out_at = out_h + (size_t)ROWS_ * D_;

    const dim3 blk(256);

    // --- node feature fusion ---
    gemm_tiled<<<dim3(4, 3), blk, 0, stream>>>(
        Wnp, Wrf, 256, 256, 256,
        nullptr, nullptr, 0, 0, 0,
        nullptr, Wcomb, 360, 256, 256, 0, 0, 0);
    biascomb_kernel<<<1, 256, 0, stream>>>(bnp, Wrf, brf, bcomb);
    gemm_tiled<<<dim3(4, 180), blk, 0, stream>>>(
        mind, Wcomb, 360, 360, 256,
        roi, Wrf + 256 * 256, 256, 256, 256,
        bcomb, nf, ROWS_, 256, 256, 0, 0, 0);
    ln_gelu_kernel<<<ROWS_, 64, 0, stream>>>(nf, ln_g, ln_b);

    // --- GAT layer 0 (dh=32) ---
    gemm_tiled<<<dim3(4, 180), blk, 0, stream>>>(
        nf, gatW0, 256, 256, 256,
        nullptr, nullptr, 0, 0, 0,
        nullptr, ht01, ROWS_, 256, 256, 0, 0, 0);
    eiej_kernel<32><<<ROWS_, 64, 0, stream>>>(ht01, gata0, ei_b, ej_b);
    gat_agg<32><<<dim3(12, B_ * H_), blk, 0, stream>>>(ht01, ei_b, ej_b, h1);

    // --- GAT layer 1 (dh=32) ---
    gemm_tiled<<<dim3(4, 180), blk, 0, stream>>>(
        h1, gatW1, 256, 256, 256,
        nullptr, nullptr, 0, 0, 0,
        nullptr, ht01, ROWS_, 256, 256, 0, 0, 0);
    eiej_kernel<32><<<ROWS_, 64, 0, stream>>>(ht01, gata1, ei_b, ej_b);
    gat_agg<32><<<dim3(12, B_ * H_), blk, 0, stream>>>(ht01, ei_b, ej_b, h2);

    // --- GAT layer 2 (collapsed): G_h = gatW2_h @ projW_h; out = sum_h a_h@(h2@G_h)
    gemm_tiled<<<dim3(4, 2, 8), blk, 0, stream>>>(
        gatW2, projW, 256, 2048, 256,
        nullptr, nullptr, 0, 0, 0,
        nullptr, Gbuf, 256, 256, 256,
        /*sA=*/256, /*sB=*/(size_t)256 * 256, /*sC=*/(size_t)256 * 256);
    uv_kernel<<<8, 256, 0, stream>>>(gatW2, gata2, uvec, vvec);
    eiej2_kernel<<<ROWS_, 64, 0, stream>>>(h2, uvec, vvec, ei_b, ej_b);

    for (int h = 0; h < H_; ++h) {
        gemm_tiled<<<dim3(4, 180), blk, 0, stream>>>(
            h2, Gbuf + (size_t)h * 256 * 256, 256, 256, 256,
            nullptr, nullptr, 0, 0, 0,
            nullptr, Z, ROWS_, 256, 256, 0, 0, 0);
        gat2_agg<<<dim3(12, B_), blk, 0, stream>>>(
            Z, ei_b, ej_b, projb, out_h, h);
    }

    // --- attention readout ---
    rownorm_kernel<<<ROWS_, 64, 0, stream>>>(out_h, norms);
    softmax_n_kernel<<<B_, 64, 0, stream>>>(norms, out_at);
    ge_kernel<<<B_, 256, 0, stream>>>(out_at, out_h, ge0);
    mlp_kernel<<<B_, 256, 0, stream>>>(ge0, Wr1, br1, ge1, 1);
    mlp_kernel<<<B_, 256, 0, stream>>>(ge1, Wr2, br2, out_ge, 0);
}

// Round 7
// 2408.470 us; speedup vs baseline: 2.2143x; 1.1016x over previous
//
#include <hip/hip_runtime.h>
#include <hip/hip_bf16.h>
#include <math.h>

// ---------------------------------------------------------------------------
// PriorEnhancedMindEncoder forward, fp32.
// Shapes: B=64, N=360, DH=256, H=8. dh(GAT0/1)=32, dh(GAT2)=256.
//
// Dead-code: adj_norm strictly positive -> GAT mask all-true -> group_prior/
// Wp1/Wp2 branch never influences outputs. Skipped.
// Fusion 1: nf = mind@(Wnp@Wrf_top) + roi@Wrf_bot + (bnp@Wrf_top+brf), LN+GELU.
// Fusion 2: GAT2 collapse: out = sum_h alpha_h @ (h2 @ G_h), G_h = gatW2_h@projW_h.
// R3: gemm 128x64 tile, 8x4 microtile, K-step 32, dbuf LDS (251us -> ~60us).
// R5: aggregates rebuilt register-tiled (R4: LDS-pipe-bound broadcast reads,
//     gat2_agg ~1.4ms total). Per m: 1 ds_read_b128 of p^T amortized over
//     32 FMAs (gat2) / 16 FMAs (gat32); unnormalized p + epilogue 1/rowsum;
//     rowmax via monotonic-lrelu: rmax_n = lrelu(ei_n + max_m ej_m).
//     (Resubmitted unchanged after R5/R6 GPUAcquisitionTimeouts.)
// ---------------------------------------------------------------------------

#define B_ 64
#define N_ 360
#define D_ 256
#define H_ 8
#define ROWS_ (B_ * N_)   // 23040

__device__ __forceinline__ float gelu_f(float x) {
    return 0.5f * x * (1.f + erff(x * 0.70710678118654752440f));
}

// ---------------------------------------------------------------------------
// Tiled fp32 GEMM: C[M,N] = A1[M,K1]@B1[K1,N] (+ A2[M,K2]@B2[K2,N]) + bias
// 128x64 tile, 256 threads, 8x4 microtile, K-step 32, double-buffered LDS.
// ---------------------------------------------------------------------------
__global__ __launch_bounds__(256) void gemm_tiled(
    const float* __restrict__ A1, const float* __restrict__ B1, int K1, int lda1, int ldb1,
    const float* __restrict__ A2, const float* __restrict__ B2, int K2, int lda2, int ldb2,
    const float* __restrict__ bias, float* __restrict__ C, int M, int N, int ldc,
    size_t sA, size_t sB, size_t sC)
{
    __shared__ float As[2][32][132];
    __shared__ float Bs[2][32][64];
    const int tid = threadIdx.x;
    const int z = blockIdx.z;
    const int bm = blockIdx.y * 128;
    const int bn = blockIdx.x * 64;
    const int tr = (tid >> 4) * 8;
    const int tc = (tid & 15) * 4;
    const int lar = tid >> 3;
    const int lak = (tid & 7) * 4;
    const int lbk = tid >> 4;
    const int lbc = (tid & 15) * 4;

    float acc[8][4] = {};
    float4 rA[4], rB[2];

    for (int pass = 0; pass < 2; ++pass) {
        const float* Ab = pass ? A2 : A1;
        const float* Bb = pass ? B2 : B1;
        if (Ab == nullptr) continue;
        const float* A  = Ab + (pass ? (size_t)0 : (size_t)z * sA);
        const float* Bm = Bb + (pass ? (size_t)0 : (size_t)z * sB);
        const int K   = pass ? K2 : K1;
        const int lda = pass ? lda2 : lda1;
        const int ldb = pass ? ldb2 : ldb1;
        const int S = (K + 31) >> 5;

        auto loadA = [&](int s) {
            const int k0 = s << 5;
            #pragma unroll
            for (int j = 0; j < 4; ++j) {
                const int gr = bm + lar + j * 32;
                const int gk = k0 + lak;
                float4 v; v.x = v.y = v.z = v.w = 0.f;
                if (gr < M) {
                    if (gk + 3 < K) {
                        v = *(const float4*)&A[(size_t)gr * lda + gk];
                    } else {
                        float t0 = 0.f, t1 = 0.f, t2 = 0.f, t3 = 0.f;
                        if (gk + 0 < K) t0 = A[(size_t)gr * lda + gk + 0];
                        if (gk + 1 < K) t1 = A[(size_t)gr * lda + gk + 1];
                        if (gk + 2 < K) t2 = A[(size_t)gr * lda + gk + 2];
                        if (gk + 3 < K) t3 = A[(size_t)gr * lda + gk + 3];
                        v.x = t0; v.y = t1; v.z = t2; v.w = t3;
                    }
                }
                rA[j] = v;
            }
        };
        auto loadB = [&](int s) {
            const int k0 = s << 5;
            #pragma unroll
            for (int j = 0; j < 2; ++j) {
                const int gk = k0 + lbk + j * 16;
                float4 v; v.x = v.y = v.z = v.w = 0.f;
                if (gk < K) v = *(const float4*)&Bm[(size_t)gk * ldb + bn + lbc];
                rB[j] = v;
            }
        };
        auto storeA = [&](int buf) {
            #pragma unroll
            for (int j = 0; j < 4; ++j) {
                const int row = lar + j * 32;
                As[buf][lak + 0][row] = rA[j].x;
                As[buf][lak + 1][row] = rA[j].y;
                As[buf][lak + 2][row] = rA[j].z;
                As[buf][lak + 3][row] = rA[j].w;
            }
        };
        auto storeB = [&](int buf) {
            #pragma unroll
            for (int j = 0; j < 2; ++j)
                *(float4*)&Bs[buf][lbk + j * 16][lbc] = rB[j];
        };

        loadA(0); loadB(0);
        storeA(0); storeB(0);
        __syncthreads();
        for (int s = 0; s < S; ++s) {
            const int cur = s & 1;
            if (s + 1 < S) { loadA(s + 1); loadB(s + 1); }
            #pragma unroll
            for (int k = 0; k < 32; ++k) {
                const float4 a0 = *(const float4*)&As[cur][k][tr];
                const float4 a1 = *(const float4*)&As[cur][k][tr + 4];
                const float4 bv = *(const float4*)&Bs[cur][k][tc];
                const float av[8] = {a0.x, a0.y, a0.z, a0.w, a1.x, a1.y, a1.z, a1.w};
                const float bb[4] = {bv.x, bv.y, bv.z, bv.w};
                #pragma unroll
                for (int i = 0; i < 8; ++i)
                    #pragma unroll
                    for (int j = 0; j < 4; ++j)
                        acc[i][j] += av[i] * bb[j];
            }
            if (s + 1 < S) { storeA(cur ^ 1); storeB(cur ^ 1); }
            __syncthreads();
        }
    }

    float4 bz; bz.x = bz.y = bz.z = bz.w = 0.f;
    if (bias) bz = *(const float4*)&bias[bn + tc];
    float* Cz = C + (size_t)z * sC;
    #pragma unroll
    for (int i = 0; i < 8; ++i) {
        const int r = bm + tr + i;
        if (r < M) {
            float4 o;
            o.x = acc[i][0] + bz.x;
            o.y = acc[i][1] + bz.y;
            o.z = acc[i][2] + bz.z;
            o.w = acc[i][3] + bz.w;
            *(float4*)&Cz[(size_t)r * ldc + bn + tc] = o;
        }
    }
}

// bias_comb[c] = brf[c] + sum_k bnp[k] * Wrf[k, c]
__global__ __launch_bounds__(256) void biascomb_kernel(
    const float* __restrict__ bnp, const float* __restrict__ Wrf,
    const float* __restrict__ brf, float* __restrict__ bcomb)
{
    int c = threadIdx.x;
    float acc = brf[c];
    for (int k = 0; k < 256; ++k) acc += bnp[k] * Wrf[k * 256 + c];
    bcomb[c] = acc;
}

// u[h][i] = sum_j gatW2[i, h*256+j] * a2[h, j]; v[h][i] with a2[h, 256+j]
__global__ __launch_bounds__(256) void uv_kernel(
    const float* __restrict__ gatW2, const float* __restrict__ a2,
    float* __restrict__ u, float* __restrict__ v)
{
    const int h = blockIdx.x;
    const int i = threadIdx.x;
    const float* wrow = gatW2 + (size_t)i * 2048 + h * 256;
    const float* ai = a2 + h * 512;
    float su = 0.f, sv = 0.f;
    for (int j = 0; j < 256; ++j) {
        float w = wrow[j];
        su += w * ai[j];
        sv += w * ai[256 + j];
    }
    u[h * 256 + i] = su;
    v[h * 256 + i] = sv;
}

// LayerNorm(eps=1e-5) + exact GELU, in-place on rows of 256. 1 wave per row.
__global__ __launch_bounds__(64) void ln_gelu_kernel(
    float* __restrict__ x, const float* __restrict__ g, const float* __restrict__ b)
{
    const size_t row = blockIdx.x;
    const int t = threadIdx.x;
    float4 v = *(const float4*)&x[row * 256 + t * 4];
    float s = v.x + v.y + v.z + v.w;
    #pragma unroll
    for (int m = 1; m < 64; m <<= 1) s += __shfl_xor(s, m);
    float mean = s * (1.f / 256.f);
    float dx = v.x - mean, dy = v.y - mean, dz = v.z - mean, dw = v.w - mean;
    float q = dx * dx + dy * dy + dz * dz + dw * dw;
    #pragma unroll
    for (int m = 1; m < 64; m <<= 1) q += __shfl_xor(q, m);
    float rstd = 1.f / sqrtf(q * (1.f / 256.f) + 1e-5f);
    float4 gg = *(const float4*)&g[t * 4];
    float4 bb = *(const float4*)&b[t * 4];
    float4 r;
    r.x = gelu_f(dx * rstd * gg.x + bb.x);
    r.y = gelu_f(dy * rstd * gg.y + bb.y);
    r.z = gelu_f(dz * rstd * gg.z + bb.z);
    r.w = gelu_f(dw * rstd * gg.w + bb.w);
    *(float4*)&x[row * 256 + t * 4] = r;
}

// ei/ej for GAT0/1
template <int DH>
__global__ __launch_bounds__(64) void eiej_kernel(
    const float* __restrict__ ht, const float* __restrict__ a,
    float* __restrict__ ei, float* __restrict__ ej)
{
    const size_t row = blockIdx.x;
    const int t = threadIdx.x;
    constexpr int E = (H_ * DH) / 64;
    const int h = t >> 3;
    const int d0 = (t & 7) * E;
    const float* hp = ht + row * (H_ * DH) + h * DH + d0;
    const float* ap = a + h * 2 * DH + d0;
    float se = 0.f, sj = 0.f;
    #pragma unroll
    for (int i = 0; i < E; i += 4) {
        float4 x = *(const float4*)&hp[i];
        float4 u = *(const float4*)&ap[i];
        float4 w = *(const float4*)&ap[DH + i];
        se += x.x * u.x + x.y * u.y + x.z * u.z + x.w * u.w;
        sj += x.x * w.x + x.y * w.y + x.z * w.z + x.w * w.w;
    }
    se += __shfl_xor(se, 1); sj += __shfl_xor(sj, 1);
    se += __shfl_xor(se, 2); sj += __shfl_xor(sj, 2);
    se += __shfl_xor(se, 4); sj += __shfl_xor(sj, 4);
    if ((t & 7) == 0) {
        ei[row * H_ + h] = se;
        ej[row * H_ + h] = sj;
    }
}

// ei2/ej2 for GAT2
__global__ __launch_bounds__(64) void eiej2_kernel(
    const float* __restrict__ h2, const float* __restrict__ u,
    const float* __restrict__ v, float* __restrict__ ei, float* __restrict__ ej)
{
    const size_t row = blockIdx.x;
    const int t = threadIdx.x;
    const int h = t >> 3;
    const int d0 = (t & 7) * 32;
    const float* hp = h2 + row * 256 + d0;
    const float* up = u + h * 256 + d0;
    const float* vp = v + h * 256 + d0;
    float se = 0.f, sj = 0.f;
    #pragma unroll
    for (int i = 0; i < 32; i += 4) {
        float4 x = *(const float4*)&hp[i];
        float4 uu = *(const float4*)&up[i];
        float4 vv = *(const float4*)&vp[i];
        se += x.x * uu.x + x.y * uu.y + x.z * uu.z + x.w * uu.w;
        sj += x.x * vv.x + x.y * vv.y + x.z * vv.z + x.w * vv.w;
    }
    se += __shfl_xor(se, 1); sj += __shfl_xor(sj, 1);
    se += __shfl_xor(se, 2); sj += __shfl_xor(sj, 2);
    se += __shfl_xor(se, 4); sj += __shfl_xor(sj, 4);
    if ((t & 7) == 0) {
        ei[row * H_ + h] = se;
        ej[row * H_ + h] = sj;
    }
}

// ---------------------------------------------------------------------------
// GAT0/1 aggregation, register-tiled. Block: 256 thr = 4 m-quarters x
// (8 row-groups x 8 col-groups), 4x4 microtile. Tile: 32 rows x 32 cols
// of one (b,h). p^T in LDS [m][r]; V read from global (L1/L2-cached).
// ---------------------------------------------------------------------------
__global__ __launch_bounds__(256) void gat_agg32(
    const float* __restrict__ ht, const float* __restrict__ ei,
    const float* __restrict__ ej, float* __restrict__ out)
{
    __shared__ float scT[N_][32];     // 46080 B; aliased as reduce buffer later
    __shared__ float ejs[N_];
    __shared__ float eis[32];
    __shared__ float psum[8][32];
    __shared__ float rinv_s[32];
    __shared__ float red4[4];
    const int tid = threadIdx.x;
    const int bh = blockIdx.y;
    const int b = bh >> 3, h = bh & 7;
    const int n0 = blockIdx.x * 32;
    const int nrows = min(32, N_ - n0);

    for (int m = tid; m < N_; m += 256) ejs[m] = ej[(b * N_ + m) * H_ + h];
    if (tid < 32) eis[tid] = (tid < nrows) ? ei[(size_t)(b * N_ + n0 + tid) * H_ + h] : 0.f;
    __syncthreads();

    // max_m ej (lrelu monotonic -> rowmax = lrelu(ei_r + maxej))
    float mx = -1e30f;
    for (int m = tid; m < N_; m += 256) mx = fmaxf(mx, ejs[m]);
    #pragma unroll
    for (int s = 1; s < 64; s <<= 1) mx = fmaxf(mx, __shfl_xor(mx, s));
    if ((tid & 63) == 0) red4[tid >> 6] = mx;
    __syncthreads();
    const float maxej = fmaxf(fmaxf(red4[0], red4[1]), fmaxf(red4[2], red4[3]));

    {   // p (unnormalized) + rowsum. thread = (r = tid&31, sub = tid>>5)
        const int r = tid & 31, sub = tid >> 5;
        const float ei_r = eis[r];
        float mrow = ei_r + maxej;
        mrow = mrow > 0.f ? mrow : 0.2f * mrow;
        float s = 0.f;
        for (int m = sub; m < N_; m += 8) {
            float e = ei_r + ejs[m];
            e = e > 0.f ? e : 0.2f * e;
            float p = __expf(e - mrow);
            scT[m][r] = p;
            s += p;
        }
        psum[sub][r] = s;
    }
    __syncthreads();
    if (tid < 32) {
        float s = psum[0][tid] + psum[1][tid] + psum[2][tid] + psum[3][tid]
                + psum[4][tid] + psum[5][tid] + psum[6][tid] + psum[7][tid];
        rinv_s[tid] = 1.f / s;
    }
    __syncthreads();

    // phase 2: acc[4r][4c] over this thread's m-quarter
    const int mq = tid >> 6;
    const int rg = (tid >> 3) & 7;
    const int cg = tid & 7;
    const float* Vp = ht + (size_t)b * N_ * D_ + h * 32 + cg * 4;
    float acc[4][4] = {};
    for (int m = mq; m < N_; m += 4) {
        const float4 a4 = *(const float4*)&scT[m][rg * 4];
        const float4 v4 = *(const float4*)&Vp[(size_t)m * D_];
        const float a[4] = {a4.x, a4.y, a4.z, a4.w};
        const float v[4] = {v4.x, v4.y, v4.z, v4.w};
        #pragma unroll
        for (int i = 0; i < 4; ++i)
            #pragma unroll
            for (int j = 0; j < 4; ++j)
                acc[i][j] += a[i] * v[j];
    }
    __syncthreads();

    // cross-quarter reduce via LDS (aliased over scT; 17-float lane stride
    // keeps banks conflict-free). red[mq*1088 + lane*17 + k], lane = rg*8+cg.
    float* red = &scT[0][0];
    {
        float* rp = red + mq * 1088 + (rg * 8 + cg) * 17;
        #pragma unroll
        for (int i = 0; i < 4; ++i)
            #pragma unroll
            for (int j = 0; j < 4; ++j)
                rp[i * 4 + j] = acc[i][j];
    }
    __syncthreads();
    for (int o = tid; o < 1024; o += 256) {
        const int lane = o >> 4, k = o & 15;
        const float v = red[0 * 1088 + lane * 17 + k] + red[1 * 1088 + lane * 17 + k]
                      + red[2 * 1088 + lane * 17 + k] + red[3 * 1088 + lane * 17 + k];
        const int rgg = lane >> 3, cgg = lane & 7, i = k >> 2, j = k & 3;
        const int r = rgg * 4 + i, c = cgg * 4 + j;
        if (r < nrows)
            out[(size_t)(b * N_ + n0 + r) * D_ + h * 32 + c] = v * rinv_s[r];
    }
}

// ---------------------------------------------------------------------------
// GAT2 aggregate-accumulate for head h, register-tiled. Block: 256 thr =
// 8 row-groups x 32 col-groups, 4x8 microtile. Tile: 32 rows x 256 cols.
//   out[b, rows, :] (+)= softmax_m(lrelu(ei+ej)) @ Z[b]  (+ projb if h==0)
// ---------------------------------------------------------------------------
__global__ __launch_bounds__(256) void gat2_agg(
    const float* __restrict__ Z, const float* __restrict__ ei,
    const float* __restrict__ ej, const float* __restrict__ projb,
    float* __restrict__ out, int h)
{
    __shared__ float scT[N_][32];
    __shared__ float ejs[N_];
    __shared__ float eis[32];
    __shared__ float psum[8][32];
    __shared__ float rinv_s[32];
    __shared__ float red4[4];
    const int tid = threadIdx.x;
    const int b = blockIdx.y;
    const int n0 = blockIdx.x * 32;
    const int nrows = min(32, N_ - n0);

    for (int m = tid; m < N_; m += 256) ejs[m] = ej[(b * N_ + m) * H_ + h];
    if (tid < 32) eis[tid] = (tid < nrows) ? ei[(size_t)(b * N_ + n0 + tid) * H_ + h] : 0.f;
    __syncthreads();

    float mx = -1e30f;
    for (int m = tid; m < N_; m += 256) mx = fmaxf(mx, ejs[m]);
    #pragma unroll
    for (int s = 1; s < 64; s <<= 1) mx = fmaxf(mx, __shfl_xor(mx, s));
    if ((tid & 63) == 0) red4[tid >> 6] = mx;
    __syncthreads();
    const float maxej = fmaxf(fmaxf(red4[0], red4[1]), fmaxf(red4[2], red4[3]));

    {
        const int r = tid & 31, sub = tid >> 5;
        const float ei_r = eis[r];
        float mrow = ei_r + maxej;
        mrow = mrow > 0.f ? mrow : 0.2f * mrow;
        float s = 0.f;
        for (int m = sub; m < N_; m += 8) {
            float e = ei_r + ejs[m];
            e = e > 0.f ? e : 0.2f * e;
            float p = __expf(e - mrow);
            scT[m][r] = p;
            s += p;
        }
        psum[sub][r] = s;
    }
    __syncthreads();
    if (tid < 32) {
        float s = psum[0][tid] + psum[1][tid] + psum[2][tid] + psum[3][tid]
                + psum[4][tid] + psum[5][tid] + psum[6][tid] + psum[7][tid];
        rinv_s[tid] = 1.f / s;
    }
    __syncthreads();

    // phase 2: 4 rows x 8 cols per thread, full m sweep
    const int rg = tid >> 5;          // 0..7 -> rows rg*4..+3
    const int cg = tid & 31;          // 0..31 -> cols cg*8..+7
    const float* Vp = Z + (size_t)b * N_ * D_ + cg * 8;
    float acc[4][8] = {};
    #pragma unroll 2
    for (int m = 0; m < N_; ++m) {
        const float4 a4 = *(const float4*)&scT[m][rg * 4];
        const float4 v0 = *(const float4*)&Vp[(size_t)m * D_];
        const float4 v1 = *(const float4*)&Vp[(size_t)m * D_ + 4];
        const float a[4] = {a4.x, a4.y, a4.z, a4.w};
        const float v[8] = {v0.x, v0.y, v0.z, v0.w, v1.x, v1.y, v1.z, v1.w};
        #pragma unroll
        for (int i = 0; i < 4; ++i)
            #pragma unroll
            for (int j = 0; j < 8; ++j)
                acc[i][j] += a[i] * v[j];
    }

    #pragma unroll
    for (int i = 0; i < 4; ++i) {
        const int r = rg * 4 + i;
        if (r < nrows) {
            const float ri = rinv_s[r];
            float* op = out + (size_t)(b * N_ + n0 + r) * D_ + cg * 8;
            if (h == 0) {
                const float4 p0 = *(const float4*)&projb[cg * 8];
                const float4 p1 = *(const float4*)&projb[cg * 8 + 4];
                float4 o0, o1;
                o0.x = acc[i][0] * ri + p0.x; o0.y = acc[i][1] * ri + p0.y;
                o0.z = acc[i][2] * ri + p0.z; o0.w = acc[i][3] * ri + p0.w;
                o1.x = acc[i][4] * ri + p1.x; o1.y = acc[i][5] * ri + p1.y;
                o1.z = acc[i][6] * ri + p1.z; o1.w = acc[i][7] * ri + p1.w;
                *(float4*)&op[0] = o0;
                *(float4*)&op[4] = o1;
            } else {
                float4 o0 = *(const float4*)&op[0];
                float4 o1 = *(const float4*)&op[4];
                o0.x += acc[i][0] * ri; o0.y += acc[i][1] * ri;
                o0.z += acc[i][2] * ri; o0.w += acc[i][3] * ri;
                o1.x += acc[i][4] * ri; o1.y += acc[i][5] * ri;
                o1.z += acc[i][6] * ri; o1.w += acc[i][7] * ri;
                *(float4*)&op[0] = o0;
                *(float4*)&op[4] = o1;
            }
        }
    }
}

// row L2 norm of h rows (256 wide), 1 wave per row
__global__ __launch_bounds__(64) void rownorm_kernel(
    const float* __restrict__ h, float* __restrict__ nrm)
{
    const size_t row = blockIdx.x;
    const int t = threadIdx.x;
    float4 v = *(const float4*)&h[row * 256 + t * 4];
    float s = v.x * v.x + v.y * v.y + v.z * v.z + v.w * v.w;
    #pragma unroll
    for (int m = 1; m < 64; m <<= 1) s += __shfl_xor(s, m);
    if (t == 0) nrm[row] = sqrtf(s);
}

// softmax over N=360 per batch, 1 wave per batch
__global__ __launch_bounds__(64) void softmax_n_kernel(
    const float* __restrict__ nrm, float* __restrict__ attn)
{
    const int b = blockIdx.x;
    const int t = threadIdx.x;
    float v[6];
    float mx = -1e30f;
    #pragma unroll
    for (int i = 0; i < 6; ++i) {
        int m = t + i * 64;
        v[i] = (m < N_) ? nrm[b * N_ + m] : -1e30f;
        mx = fmaxf(mx, v[i]);
    }
    #pragma unroll
    for (int m = 1; m < 64; m <<= 1) mx = fmaxf(mx, __shfl_xor(mx, m));
    float s = 0.f;
    #pragma unroll
    for (int i = 0; i < 6; ++i) {
        int m = t + i * 64;
        float p = (m < N_) ? __expf(v[i] - mx) : 0.f;
        v[i] = p;
        s += p;
    }
    #pragma unroll
    for (int m = 1; m < 64; m <<= 1) s += __shfl_xor(s, m);
    const float inv = 1.f / s;
    #pragma unroll
    for (int i = 0; i < 6; ++i) {
        int m = t + i * 64;
        if (m < N_) attn[b * N_ + m] = v[i] * inv;
    }
}

// ge[b,c] = sum_n attn[b,n] * h[b,n,c]
__global__ __launch_bounds__(256) void ge_kernel(
    const float* __restrict__ attn, const float* __restrict__ h, float* __restrict__ ge)
{
    __shared__ float a[N_];
    const int b = blockIdx.x;
    const int t = threadIdx.x;
    for (int m = t; m < N_; m += 256) a[m] = attn[b * N_ + m];
    __syncthreads();
    float acc = 0.f;
    const float* hp = h + (size_t)b * N_ * 256 + t;
    for (int m = 0; m < N_; ++m) acc += a[m] * hp[(size_t)m * 256];
    ge[b * 256 + t] = acc;
}

// Y[b,c] = (gelu?)(X[b,:] @ W[:,c] + bias[c])
__global__ __launch_bounds__(256) void mlp_kernel(
    const float* __restrict__ X, const float* __restrict__ W,
    const float* __restrict__ bias, float* __restrict__ Y, int applyGelu)
{
    __shared__ float xs[256];
    const int b = blockIdx.x;
    const int t = threadIdx.x;
    xs[t] = X[b * 256 + t];
    __syncthreads();
    float acc = bias[t];
    for (int k = 0; k < 256; ++k) acc += xs[k] * W[k * 256 + t];
    if (applyGelu) acc = gelu_f(acc);
    Y[b * 256 + t] = acc;
}

// ---------------------------------------------------------------------------

extern "C" void kernel_launch(void* const* d_in, const int* in_sizes, int n_in,
                              void* d_out, int out_size, void* d_ws, size_t ws_size,
                              hipStream_t stream) {
    const float* mind  = (const float*)d_in[0];
    const float* roi   = (const float*)d_in[1];
    const float* Wnp   = (const float*)d_in[3];
    const float* bnp   = (const float*)d_in[4];
    const float* Wrf   = (const float*)d_in[5];
    const float* brf   = (const float*)d_in[6];
    const float* ln_g  = (const float*)d_in[7];
    const float* ln_b  = (const float*)d_in[8];
    const float* gatW0 = (const float*)d_in[13];
    const float* gata0 = (const float*)d_in[14];
    const float* gatW1 = (const float*)d_in[15];
    const float* gata1 = (const float*)d_in[16];
    const float* gatW2 = (const float*)d_in[17];
    const float* gata2 = (const float*)d_in[18];
    const float* projW = (const float*)d_in[19];
    const float* projb = (const float*)d_in[20];
    const float* Wr1   = (const float*)d_in[21];
    const float* br1   = (const float*)d_in[22];
    const float* Wr2   = (const float*)d_in[23];
    const float* br2   = (const float*)d_in[24];

    const size_t SZ = (size_t)ROWS_ * D_;       // 5,898,240 floats
    float* ws    = (float*)d_ws;
    float* nf    = ws;
    float* h1    = nf + SZ;
    float* h2    = h1 + SZ;
    float* ht01  = h2 + SZ;
    float* Z     = ht01 + SZ;
    float* ei_b  = Z + SZ;
    float* ej_b  = ei_b + ROWS_ * H_;
    float* Wcomb = ej_b + ROWS_ * H_;
    float* bcomb = Wcomb + 360 * 256;
    float* Gbuf  = bcomb + 256;
    float* uvec  = Gbuf + 8 * 256 * 256;
    float* vvec  = uvec + 8 * 256;
    float* norms = vvec + 8 * 256;
    float* ge0   = norms + ROWS_;
    float* ge1   = ge0 + B_ * D_;

    const size_t need = (size_t)(ge1 + B_ * D_ - ws) * sizeof(float);
    if (ws_size < need) return;

    float* out    = (float*)d_out;
    float* out_ge = out;
    float* out_h  = out + (size_t)B_ * D_;
    float* out_at = out_h + (size_t)ROWS_ * D_;

    const dim3 blk(256);

    // --- node feature fusion ---
    gemm_tiled<<<dim3(4, 3), blk, 0, stream>>>(
        Wnp, Wrf, 256, 256, 256,
        nullptr, nullptr, 0, 0, 0,
        nullptr, Wcomb, 360, 256, 256, 0, 0, 0);
    biascomb_kernel<<<1, 256, 0, stream>>>(bnp, Wrf, brf, bcomb);
    gemm_tiled<<<dim3(4, 180), blk, 0, stream>>>(
        mind, Wcomb, 360, 360, 256,
        roi, Wrf + 256 * 256, 256, 256, 256,
        bcomb, nf, ROWS_, 256, 256, 0, 0, 0);
    ln_gelu_kernel<<<ROWS_, 64, 0, stream>>>(nf, ln_g, ln_b);

    // --- GAT layer 0 (dh=32) ---
    gemm_tiled<<<dim3(4, 180), blk, 0, stream>>>(
        nf, gatW0, 256, 256, 256,
        nullptr, nullptr, 0, 0, 0,
        nullptr, ht01, ROWS_, 256, 256, 0, 0, 0);
    eiej_kernel<32><<<ROWS_, 64, 0, stream>>>(ht01, gata0, ei_b, ej_b);
    gat_agg32<<<dim3(12, B_ * H_), blk, 0, stream>>>(ht01, ei_b, ej_b, h1);

    // --- GAT layer 1 (dh=32) ---
    gemm_tiled<<<dim3(4, 180), blk, 0, stream>>>(
        h1, gatW1, 256, 256, 256,
        nullptr, nullptr, 0, 0, 0,
        nullptr, ht01, ROWS_, 256, 256, 0, 0, 0);
    eiej_kernel<32><<<ROWS_, 64, 0, stream>>>(ht01, gata1, ei_b, ej_b);
    gat_agg32<<<dim3(12, B_ * H_), blk, 0, stream>>>(ht01, ei_b, ej_b, h2);

    // --- GAT layer 2 (collapsed): G_h = gatW2_h @ projW_h; out = sum_h a_h@(h2@G_h)
    gemm_tiled<<<dim3(4, 2, 8), blk, 0, stream>>>(
        gatW2, projW, 256, 2048, 256,
        nullptr, nullptr, 0, 0, 0,
        nullptr, Gbuf, 256, 256, 256,
        256, (size_t)256 * 256, (size_t)256 * 256);
    uv_kernel<<<8, 256, 0, stream>>>(gatW2, gata2, uvec, vvec);
    eiej2_kernel<<<ROWS_, 64, 0, stream>>>(h2, uvec, vvec, ei_b, ej_b);

    for (int h = 0; h < H_; ++h) {
        gemm_tiled<<<dim3(4, 180), blk, 0, stream>>>(
            h2, Gbuf + (size_t)h * 256 * 256, 256, 256, 256,
            nullptr, nullptr, 0, 0, 0,
            nullptr, Z, ROWS_, 256, 256, 0, 0, 0);
        gat2_agg<<<dim3(12, B_), blk, 0, stream>>>(
            Z, ei_b, ej_b, projb, out_h, h);
    }

    // --- attention readout ---
    rownorm_kernel<<<ROWS_, 64, 0, stream>>>(out_h, norms);
    softmax_n_kernel<<<B_, 64, 0, stream>>>(norms, out_at);
    ge_kernel<<<B_, 256, 0, stream>>>(out_at, out_h, ge0);
    mlp_kernel<<<B_, 256, 0, stream>>>(ge0, Wr1, br1, ge1, 1);
    mlp_kernel<<<B_, 256, 0, stream>>>(ge1, Wr2, br2, out_ge, 0);
}

// Round 8
// 2048.327 us; speedup vs baseline: 2.6036x; 1.1758x over previous
//
#include <hip/hip_runtime.h>
#include <hip/hip_bf16.h>
#include <math.h>

// ---------------------------------------------------------------------------
// PriorEnhancedMindEncoder forward, fp32.
// Shapes: B=64, N=360, DH=256, H=8. dh(GAT0/1)=32, dh(GAT2)=256.
//
// Dead-code: adj_norm strictly positive -> GAT mask all-true -> group_prior/
// Wp1/Wp2 branch skipped.
// Fusion 1: nf = mind@(Wnp@Wrf_top) + roi@Wrf_bot + (bnp@Wrf_top+brf), LN+GELU.
// Fusion 2: GAT2 collapse: out = sum_h alpha_h @ (h2 @ G_h), G_h = gatW2_h@projW_h.
// R3: gemm 128x64 tile, 8x4 microtile, K-step 32, dbuf LDS.
// R7: gat_agg32 was latency-bound on 128B-strided V reads (268us, VALU 30%,
//     FETCH 4x tensor). R8: gat01_agg computes all 8 heads per block so V
//     reads are full 1KB rows (gat2 pattern, chunked scores in LDS);
//     gat2_agg fused 4 heads/dispatch with register accumulator (kills 7
//     out RMW passes + serialization); Z GEMMs z-batched 2x4.
// ---------------------------------------------------------------------------

#define B_ 64
#define N_ 360
#define D_ 256
#define H_ 8
#define ROWS_ (B_ * N_)   // 23040
#define CHUNK01 30
#define SCPAD 964         // per-head score block stride (30*32 + 4), floats

__device__ __forceinline__ float gelu_f(float x) {
    return 0.5f * x * (1.f + erff(x * 0.70710678118654752440f));
}

// ---------------------------------------------------------------------------
// Tiled fp32 GEMM: C[M,N] = A1[M,K1]@B1[K1,N] (+ A2[M,K2]@B2[K2,N]) + bias
// 128x64 tile, 256 threads, 8x4 microtile, K-step 32, double-buffered LDS.
// z-batch: pass-0 A/B and C shifted by z*sA / z*sB / z*sC elements.
// ---------------------------------------------------------------------------
__global__ __launch_bounds__(256) void gemm_tiled(
    const float* __restrict__ A1, const float* __restrict__ B1, int K1, int lda1, int ldb1,
    const float* __restrict__ A2, const float* __restrict__ B2, int K2, int lda2, int ldb2,
    const float* __restrict__ bias, float* __restrict__ C, int M, int N, int ldc,
    size_t sA, size_t sB, size_t sC)
{
    __shared__ float As[2][32][132];
    __shared__ float Bs[2][32][64];
    const int tid = threadIdx.x;
    const int z = blockIdx.z;
    const int bm = blockIdx.y * 128;
    const int bn = blockIdx.x * 64;
    const int tr = (tid >> 4) * 8;
    const int tc = (tid & 15) * 4;
    const int lar = tid >> 3;
    const int lak = (tid & 7) * 4;
    const int lbk = tid >> 4;
    const int lbc = (tid & 15) * 4;

    float acc[8][4] = {};
    float4 rA[4], rB[2];

    for (int pass = 0; pass < 2; ++pass) {
        const float* Ab = pass ? A2 : A1;
        const float* Bb = pass ? B2 : B1;
        if (Ab == nullptr) continue;
        const float* A  = Ab + (pass ? (size_t)0 : (size_t)z * sA);
        const float* Bm = Bb + (pass ? (size_t)0 : (size_t)z * sB);
        const int K   = pass ? K2 : K1;
        const int lda = pass ? lda2 : lda1;
        const int ldb = pass ? ldb2 : ldb1;
        const int S = (K + 31) >> 5;

        auto loadA = [&](int s) {
            const int k0 = s << 5;
            #pragma unroll
            for (int j = 0; j < 4; ++j) {
                const int gr = bm + lar + j * 32;
                const int gk = k0 + lak;
                float4 v; v.x = v.y = v.z = v.w = 0.f;
                if (gr < M) {
                    if (gk + 3 < K) {
                        v = *(const float4*)&A[(size_t)gr * lda + gk];
                    } else {
                        float t0 = 0.f, t1 = 0.f, t2 = 0.f, t3 = 0.f;
                        if (gk + 0 < K) t0 = A[(size_t)gr * lda + gk + 0];
                        if (gk + 1 < K) t1 = A[(size_t)gr * lda + gk + 1];
                        if (gk + 2 < K) t2 = A[(size_t)gr * lda + gk + 2];
                        if (gk + 3 < K) t3 = A[(size_t)gr * lda + gk + 3];
                        v.x = t0; v.y = t1; v.z = t2; v.w = t3;
                    }
                }
                rA[j] = v;
            }
        };
        auto loadB = [&](int s) {
            const int k0 = s << 5;
            #pragma unroll
            for (int j = 0; j < 2; ++j) {
                const int gk = k0 + lbk + j * 16;
                float4 v; v.x = v.y = v.z = v.w = 0.f;
                if (gk < K) v = *(const float4*)&Bm[(size_t)gk * ldb + bn + lbc];
                rB[j] = v;
            }
        };
        auto storeA = [&](int buf) {
            #pragma unroll
            for (int j = 0; j < 4; ++j) {
                const int row = lar + j * 32;
                As[buf][lak + 0][row] = rA[j].x;
                As[buf][lak + 1][row] = rA[j].y;
                As[buf][lak + 2][row] = rA[j].z;
                As[buf][lak + 3][row] = rA[j].w;
            }
        };
        auto storeB = [&](int buf) {
            #pragma unroll
            for (int j = 0; j < 2; ++j)
                *(float4*)&Bs[buf][lbk + j * 16][lbc] = rB[j];
        };

        loadA(0); loadB(0);
        storeA(0); storeB(0);
        __syncthreads();
        for (int s = 0; s < S; ++s) {
            const int cur = s & 1;
            if (s + 1 < S) { loadA(s + 1); loadB(s + 1); }
            #pragma unroll
            for (int k = 0; k < 32; ++k) {
                const float4 a0 = *(const float4*)&As[cur][k][tr];
                const float4 a1 = *(const float4*)&As[cur][k][tr + 4];
                const float4 bv = *(const float4*)&Bs[cur][k][tc];
                const float av[8] = {a0.x, a0.y, a0.z, a0.w, a1.x, a1.y, a1.z, a1.w};
                const float bb[4] = {bv.x, bv.y, bv.z, bv.w};
                #pragma unroll
                for (int i = 0; i < 8; ++i)
                    #pragma unroll
                    for (int j = 0; j < 4; ++j)
                        acc[i][j] += av[i] * bb[j];
            }
            if (s + 1 < S) { storeA(cur ^ 1); storeB(cur ^ 1); }
            __syncthreads();
        }
    }

    float4 bz; bz.x = bz.y = bz.z = bz.w = 0.f;
    if (bias) bz = *(const float4*)&bias[bn + tc];
    float* Cz = C + (size_t)z * sC;
    #pragma unroll
    for (int i = 0; i < 8; ++i) {
        const int r = bm + tr + i;
        if (r < M) {
            float4 o;
            o.x = acc[i][0] + bz.x;
            o.y = acc[i][1] + bz.y;
            o.z = acc[i][2] + bz.z;
            o.w = acc[i][3] + bz.w;
            *(float4*)&Cz[(size_t)r * ldc + bn + tc] = o;
        }
    }
}

// bias_comb[c] = brf[c] + sum_k bnp[k] * Wrf[k, c]
__global__ __launch_bounds__(256) void biascomb_kernel(
    const float* __restrict__ bnp, const float* __restrict__ Wrf,
    const float* __restrict__ brf, float* __restrict__ bcomb)
{
    int c = threadIdx.x;
    float acc = brf[c];
    for (int k = 0; k < 256; ++k) acc += bnp[k] * Wrf[k * 256 + c];
    bcomb[c] = acc;
}

// u[h][i] = sum_j gatW2[i, h*256+j] * a2[h, j]; v[h][i] with a2[h, 256+j]
__global__ __launch_bounds__(256) void uv_kernel(
    const float* __restrict__ gatW2, const float* __restrict__ a2,
    float* __restrict__ u, float* __restrict__ v)
{
    const int h = blockIdx.x;
    const int i = threadIdx.x;
    const float* wrow = gatW2 + (size_t)i * 2048 + h * 256;
    const float* ai = a2 + h * 512;
    float su = 0.f, sv = 0.f;
    for (int j = 0; j < 256; ++j) {
        float w = wrow[j];
        su += w * ai[j];
        sv += w * ai[256 + j];
    }
    u[h * 256 + i] = su;
    v[h * 256 + i] = sv;
}

// LayerNorm(eps=1e-5) + exact GELU, in-place on rows of 256. 1 wave per row.
__global__ __launch_bounds__(64) void ln_gelu_kernel(
    float* __restrict__ x, const float* __restrict__ g, const float* __restrict__ b)
{
    const size_t row = blockIdx.x;
    const int t = threadIdx.x;
    float4 v = *(const float4*)&x[row * 256 + t * 4];
    float s = v.x + v.y + v.z + v.w;
    #pragma unroll
    for (int m = 1; m < 64; m <<= 1) s += __shfl_xor(s, m);
    float mean = s * (1.f / 256.f);
    float dx = v.x - mean, dy = v.y - mean, dz = v.z - mean, dw = v.w - mean;
    float q = dx * dx + dy * dy + dz * dz + dw * dw;
    #pragma unroll
    for (int m = 1; m < 64; m <<= 1) q += __shfl_xor(q, m);
    float rstd = 1.f / sqrtf(q * (1.f / 256.f) + 1e-5f);
    float4 gg = *(const float4*)&g[t * 4];
    float4 bb = *(const float4*)&b[t * 4];
    float4 r;
    r.x = gelu_f(dx * rstd * gg.x + bb.x);
    r.y = gelu_f(dy * rstd * gg.y + bb.y);
    r.z = gelu_f(dz * rstd * gg.z + bb.z);
    r.w = gelu_f(dw * rstd * gg.w + bb.w);
    *(float4*)&x[row * 256 + t * 4] = r;
}

// ei/ej for GAT0/1: per row: ei[h] = ht[row,h,:dh] . a[h,:dh]
template <int DH>
__global__ __launch_bounds__(64) void eiej_kernel(
    const float* __restrict__ ht, const float* __restrict__ a,
    float* __restrict__ ei, float* __restrict__ ej)
{
    const size_t row = blockIdx.x;
    const int t = threadIdx.x;
    constexpr int E = (H_ * DH) / 64;
    const int h = t >> 3;
    const int d0 = (t & 7) * E;
    const float* hp = ht + row * (H_ * DH) + h * DH + d0;
    const float* ap = a + h * 2 * DH + d0;
    float se = 0.f, sj = 0.f;
    #pragma unroll
    for (int i = 0; i < E; i += 4) {
        float4 x = *(const float4*)&hp[i];
        float4 u = *(const float4*)&ap[i];
        float4 w = *(const float4*)&ap[DH + i];
        se += x.x * u.x + x.y * u.y + x.z * u.z + x.w * u.w;
        sj += x.x * w.x + x.y * w.y + x.z * w.z + x.w * w.w;
    }
    se += __shfl_xor(se, 1); sj += __shfl_xor(sj, 1);
    se += __shfl_xor(se, 2); sj += __shfl_xor(sj, 2);
    se += __shfl_xor(se, 4); sj += __shfl_xor(sj, 4);
    if ((t & 7) == 0) {
        ei[row * H_ + h] = se;
        ej[row * H_ + h] = sj;
    }
}

// ei2/ej2 for GAT2: ei2[row,h] = h2[row,:] . u[h,:], ej2 with v.
__global__ __launch_bounds__(64) void eiej2_kernel(
    const float* __restrict__ h2, const float* __restrict__ u,
    const float* __restrict__ v, float* __restrict__ ei, float* __restrict__ ej)
{
    const size_t row = blockIdx.x;
    const int t = threadIdx.x;
    const int h = t >> 3;
    const int d0 = (t & 7) * 32;
    const float* hp = h2 + row * 256 + d0;
    const float* up = u + h * 256 + d0;
    const float* vp = v + h * 256 + d0;
    float se = 0.f, sj = 0.f;
    #pragma unroll
    for (int i = 0; i < 32; i += 4) {
        float4 x = *(const float4*)&hp[i];
        float4 uu = *(const float4*)&up[i];
        float4 vv = *(const float4*)&vp[i];
        se += x.x * uu.x + x.y * uu.y + x.z * uu.z + x.w * uu.w;
        sj += x.x * vv.x + x.y * vv.y + x.z * vv.z + x.w * vv.w;
    }
    se += __shfl_xor(se, 1); sj += __shfl_xor(sj, 1);
    se += __shfl_xor(se, 2); sj += __shfl_xor(sj, 2);
    se += __shfl_xor(se, 4); sj += __shfl_xor(sj, 4);
    if ((t & 7) == 0) {
        ei[row * H_ + h] = se;
        ej[row * H_ + h] = sj;
    }
}

// ---------------------------------------------------------------------------
// GAT0/1 aggregation, ALL 8 heads per block. Block = (ntile, b), 256 thr.
// Output tile 32 rows x 256 cols. Scores chunked: 12 chunks of 30 m in LDS
// scT[8 heads][30 m][32 r] (pad 4/head -> banks conflict-free). V = full
// contiguous ht rows (coalesced 1KB), p unnormalized + epilogue 1/rowsum.
// ---------------------------------------------------------------------------
__global__ __launch_bounds__(256) void gat01_agg(
    const float* __restrict__ ht, const float* __restrict__ ei,
    const float* __restrict__ ej, float* __restrict__ out)
{
    __shared__ float scT[8 * SCPAD];     // 30848 B
    __shared__ float ejs[8][N_];         // 11520 B  [h][m]
    __shared__ float eis[8][32];
    __shared__ float rinv_s[8][32];
    __shared__ float maxej_s[8];
    const int tid = threadIdx.x;
    const int b = blockIdx.y;
    const int n0 = blockIdx.x * 32;
    const int nrows = min(32, N_ - n0);

    for (int idx = tid; idx < N_ * H_; idx += 256) {
        const int m = idx >> 3, h = idx & 7;
        ejs[h][m] = ej[(size_t)(b * N_ + m) * H_ + h];
    }
    const int ph = tid >> 5, pr = tid & 31;    // score-role: head, row
    eis[ph][pr] = (pr < nrows) ? ei[(size_t)(b * N_ + n0 + pr) * H_ + ph] : 0.f;
    __syncthreads();

    {   // per-head max over ej (32 threads/head)
        float mx = -1e30f;
        for (int m = pr; m < N_; m += 32) mx = fmaxf(mx, ejs[ph][m]);
        mx = fmaxf(mx, __shfl_xor(mx, 1));
        mx = fmaxf(mx, __shfl_xor(mx, 2));
        mx = fmaxf(mx, __shfl_xor(mx, 4));
        mx = fmaxf(mx, __shfl_xor(mx, 8));
        mx = fmaxf(mx, __shfl_xor(mx, 16));
        if (pr == 0) maxej_s[ph] = mx;
    }
    __syncthreads();

    const float ei_r = eis[ph][pr];
    float mrow = ei_r + maxej_s[ph];
    mrow = mrow > 0.f ? mrow : 0.2f * mrow;    // lrelu monotonic -> row max
    float rsum = 0.f;

    const int rg = tid >> 5, cg = tid & 31;    // multiply-role
    const int vh = cg >> 2;                    // head owning cols cg*8..+7
    const float* Vp = ht + (size_t)b * N_ * D_ + cg * 8;
    float acc[4][8] = {};

    for (int c0 = 0; c0 < N_; c0 += CHUNK01) {
        // scores for m in [c0, c0+30)
        float* sp = scT + ph * SCPAD + pr;
        #pragma unroll 6
        for (int mm = 0; mm < CHUNK01; ++mm) {
            float e = ei_r + ejs[ph][c0 + mm];
            e = e > 0.f ? e : 0.2f * e;
            float p = __expf(e - mrow);
            sp[mm * 32] = p;
            rsum += p;
        }
        __syncthreads();
        // multiply
        const float* st = scT + vh * SCPAD + rg * 4;
        #pragma unroll 2
        for (int mm = 0; mm < CHUNK01; ++mm) {
            const int m = c0 + mm;
            const float4 a4 = *(const float4*)&st[mm * 32];
            const float4 v0 = *(const float4*)&Vp[(size_t)m * D_];
            const float4 v1 = *(const float4*)&Vp[(size_t)m * D_ + 4];
            const float a[4] = {a4.x, a4.y, a4.z, a4.w};
            const float v[8] = {v0.x, v0.y, v0.z, v0.w, v1.x, v1.y, v1.z, v1.w};
            #pragma unroll
            for (int i = 0; i < 4; ++i)
                #pragma unroll
                for (int j = 0; j < 8; ++j)
                    acc[i][j] += a[i] * v[j];
        }
        __syncthreads();
    }

    rinv_s[ph][pr] = 1.f / rsum;
    __syncthreads();

    #pragma unroll
    for (int i = 0; i < 4; ++i) {
        const int r = rg * 4 + i;
        if (r < nrows) {
            const float ri = rinv_s[vh][r];
            float* op = out + (size_t)(b * N_ + n0 + r) * D_ + cg * 8;
            float4 o0, o1;
            o0.x = acc[i][0] * ri; o0.y = acc[i][1] * ri;
            o0.z = acc[i][2] * ri; o0.w = acc[i][3] * ri;
            o1.x = acc[i][4] * ri; o1.y = acc[i][5] * ri;
            o1.z = acc[i][6] * ri; o1.w = acc[i][7] * ri;
            *(float4*)&op[0] = o0;
            *(float4*)&op[4] = o1;
        }
    }
}

// ---------------------------------------------------------------------------
// GAT2 aggregation, 4 heads per dispatch, register accumulator across heads.
// Block = (ntile, b), 256 thr, out tile 32 x 256. Per head: normalized p in
// scT[360][32] (two-exp-pass), then m-sweep with contiguous Z row reads.
// first==1: out = acc + projb; else out += acc.
// ---------------------------------------------------------------------------
__global__ __launch_bounds__(256) void gat2_agg4(
    const float* __restrict__ Zbase, size_t zstride,
    const float* __restrict__ ei, const float* __restrict__ ej,
    const float* __restrict__ projb, float* __restrict__ out,
    int hbase, int first)
{
    __shared__ float scT[N_][32];     // 46080 B
    __shared__ float ejs[N_];
    __shared__ float eis[32];
    __shared__ float psum[8][32];
    __shared__ float rinv_s[32];
    __shared__ float red4[4];
    const int tid = threadIdx.x;
    const int b = blockIdx.y;
    const int n0 = blockIdx.x * 32;
    const int nrows = min(32, N_ - n0);
    const int rg = tid >> 5, cg = tid & 31;
    const int sr = tid & 31, sub = tid >> 5;   // score-role
    float acc[4][8] = {};

    for (int hh = 0; hh < 4; ++hh) {
        const int h = hbase + hh;
        for (int m = tid; m < N_; m += 256) ejs[m] = ej[(size_t)(b * N_ + m) * H_ + h];
        if (tid < 32) eis[tid] = (tid < nrows) ? ei[(size_t)(b * N_ + n0 + tid) * H_ + h] : 0.f;
        __syncthreads();

        float mx = -1e30f;
        for (int m = tid; m < N_; m += 256) mx = fmaxf(mx, ejs[m]);
        #pragma unroll
        for (int s = 1; s < 64; s <<= 1) mx = fmaxf(mx, __shfl_xor(mx, s));
        if ((tid & 63) == 0) red4[tid >> 6] = mx;
        __syncthreads();
        const float maxej = fmaxf(fmaxf(red4[0], red4[1]), fmaxf(red4[2], red4[3]));

        const float ei_r = eis[sr];
        float mrow = ei_r + maxej;
        mrow = mrow > 0.f ? mrow : 0.2f * mrow;

        // pass A: rowsum only
        float s = 0.f;
        for (int m = sub; m < N_; m += 8) {
            float e = ei_r + ejs[m];
            e = e > 0.f ? e : 0.2f * e;
            s += __expf(e - mrow);
        }
        psum[sub][sr] = s;
        __syncthreads();
        if (tid < 32) {
            float t = psum[0][tid] + psum[1][tid] + psum[2][tid] + psum[3][tid]
                    + psum[4][tid] + psum[5][tid] + psum[6][tid] + psum[7][tid];
            rinv_s[tid] = 1.f / t;
        }
        __syncthreads();
        // pass B: store normalized p
        const float ri = rinv_s[sr];
        for (int m = sub; m < N_; m += 8) {
            float e = ei_r + ejs[m];
            e = e > 0.f ? e : 0.2f * e;
            scT[m][sr] = __expf(e - mrow) * ri;
        }
        __syncthreads();

        // multiply: acc += p_h @ Z_h (contiguous 1KB row reads)
        const float* Vp = Zbase + (size_t)hh * zstride + (size_t)b * N_ * D_ + cg * 8;
        #pragma unroll 2
        for (int m = 0; m < N_; ++m) {
            const float4 a4 = *(const float4*)&scT[m][rg * 4];
            const float4 v0 = *(const float4*)&Vp[(size_t)m * D_];
            const float4 v1 = *(const float4*)&Vp[(size_t)m * D_ + 4];
            const float a[4] = {a4.x, a4.y, a4.z, a4.w};
            const float v[8] = {v0.x, v0.y, v0.z, v0.w, v1.x, v1.y, v1.z, v1.w};
            #pragma unroll
            for (int i = 0; i < 4; ++i)
                #pragma unroll
                for (int j = 0; j < 8; ++j)
                    acc[i][j] += a[i] * v[j];
        }
        __syncthreads();   // protect ejs/scT before next head overwrites
    }

    #pragma unroll
    for (int i = 0; i < 4; ++i) {
        const int r = rg * 4 + i;
        if (r < nrows) {
            float* op = out + (size_t)(b * N_ + n0 + r) * D_ + cg * 8;
            if (first) {
                const float4 p0 = *(const float4*)&projb[cg * 8];
                const float4 p1 = *(const float4*)&projb[cg * 8 + 4];
                float4 o0, o1;
                o0.x = acc[i][0] + p0.x; o0.y = acc[i][1] + p0.y;
                o0.z = acc[i][2] + p0.z; o0.w = acc[i][3] + p0.w;
                o1.x = acc[i][4] + p1.x; o1.y = acc[i][5] + p1.y;
                o1.z = acc[i][6] + p1.z; o1.w = acc[i][7] + p1.w;
                *(float4*)&op[0] = o0;
                *(float4*)&op[4] = o1;
            } else {
                float4 o0 = *(const float4*)&op[0];
                float4 o1 = *(const float4*)&op[4];
                o0.x += acc[i][0]; o0.y += acc[i][1];
                o0.z += acc[i][2]; o0.w += acc[i][3];
                o1.x += acc[i][4]; o1.y += acc[i][5];
                o1.z += acc[i][6]; o1.w += acc[i][7];
                *(float4*)&op[0] = o0;
                *(float4*)&op[4] = o1;
            }
        }
    }
}

// row L2 norm of h rows (256 wide), 1 wave per row
__global__ __launch_bounds__(64) void rownorm_kernel(
    const float* __restrict__ h, float* __restrict__ nrm)
{
    const size_t row = blockIdx.x;
    const int t = threadIdx.x;
    float4 v = *(const float4*)&h[row * 256 + t * 4];
    float s = v.x * v.x + v.y * v.y + v.z * v.z + v.w * v.w;
    #pragma unroll
    for (int m = 1; m < 64; m <<= 1) s += __shfl_xor(s, m);
    if (t == 0) nrm[row] = sqrtf(s);
}

// softmax over N=360 per batch, 1 wave per batch
__global__ __launch_bounds__(64) void softmax_n_kernel(
    const float* __restrict__ nrm, float* __restrict__ attn)
{
    const int b = blockIdx.x;
    const int t = threadIdx.x;
    float v[6];
    float mx = -1e30f;
    #pragma unroll
    for (int i = 0; i < 6; ++i) {
        int m = t + i * 64;
        v[i] = (m < N_) ? nrm[b * N_ + m] : -1e30f;
        mx = fmaxf(mx, v[i]);
    }
    #pragma unroll
    for (int m = 1; m < 64; m <<= 1) mx = fmaxf(mx, __shfl_xor(mx, m));
    float s = 0.f;
    #pragma unroll
    for (int i = 0; i < 6; ++i) {
        int m = t + i * 64;
        float p = (m < N_) ? __expf(v[i] - mx) : 0.f;
        v[i] = p;
        s += p;
    }
    #pragma unroll
    for (int m = 1; m < 64; m <<= 1) s += __shfl_xor(s, m);
    const float inv = 1.f / s;
    #pragma unroll
    for (int i = 0; i < 6; ++i) {
        int m = t + i * 64;
        if (m < N_) attn[b * N_ + m] = v[i] * inv;
    }
}

// ge[b,c] = sum_n attn[b,n] * h[b,n,c]
__global__ __launch_bounds__(256) void ge_kernel(
    const float* __restrict__ attn, const float* __restrict__ h, float* __restrict__ ge)
{
    __shared__ float a[N_];
    const int b = blockIdx.x;
    const int t = threadIdx.x;
    for (int m = t; m < N_; m += 256) a[m] = attn[b * N_ + m];
    __syncthreads();
    float acc = 0.f;
    const float* hp = h + (size_t)b * N_ * 256 + t;
    for (int m = 0; m < N_; ++m) acc += a[m] * hp[(size_t)m * 256];
    ge[b * 256 + t] = acc;
}

// Y[b,c] = (gelu?)(X[b,:] @ W[:,c] + bias[c])
__global__ __launch_bounds__(256) void mlp_kernel(
    const float* __restrict__ X, const float* __restrict__ W,
    const float* __restrict__ bias, float* __restrict__ Y, int applyGelu)
{
    __shared__ float xs[256];
    const int b = blockIdx.x;
    const int t = threadIdx.x;
    xs[t] = X[b * 256 + t];
    __syncthreads();
    float acc = bias[t];
    for (int k = 0; k < 256; ++k) acc += xs[k] * W[k * 256 + t];
    if (applyGelu) acc = gelu_f(acc);
    Y[b * 256 + t] = acc;
}

// ---------------------------------------------------------------------------

extern "C" void kernel_launch(void* const* d_in, const int* in_sizes, int n_in,
                              void* d_out, int out_size, void* d_ws, size_t ws_size,
                              hipStream_t stream) {
    const float* mind  = (const float*)d_in[0];
    const float* roi   = (const float*)d_in[1];
    const float* Wnp   = (const float*)d_in[3];
    const float* bnp   = (const float*)d_in[4];
    const float* Wrf   = (const float*)d_in[5];
    const float* brf   = (const float*)d_in[6];
    const float* ln_g  = (const float*)d_in[7];
    const float* ln_b  = (const float*)d_in[8];
    const float* gatW0 = (const float*)d_in[13];
    const float* gata0 = (const float*)d_in[14];
    const float* gatW1 = (const float*)d_in[15];
    const float* gata1 = (const float*)d_in[16];
    const float* gatW2 = (const float*)d_in[17];
    const float* gata2 = (const float*)d_in[18];
    const float* projW = (const float*)d_in[19];
    const float* projb = (const float*)d_in[20];
    const float* Wr1   = (const float*)d_in[21];
    const float* br1   = (const float*)d_in[22];
    const float* Wr2   = (const float*)d_in[23];
    const float* br2   = (const float*)d_in[24];

    const size_t SZ = (size_t)ROWS_ * D_;       // 5,898,240 floats
    float* ws = (float*)d_ws;
    // slot plan: s0 = h2 (final); s1..s4 = zbuf (and nf/ht/h1 earlier)
    float* s0 = ws;                  // h2
    float* s1 = ws + SZ;             // nf -> zbuf[0]
    float* s2 = ws + 2 * SZ;         // ht0/ht1 -> zbuf[1]
    float* s3 = ws + 3 * SZ;         // h1 -> zbuf[2]
    float* s4 = ws + 4 * SZ;         // zbuf[3]
    float* tail  = ws + 5 * SZ;
    float* ei_b  = tail;                         // 23040*8
    float* ej_b  = ei_b + (size_t)ROWS_ * H_;
    float* Wcomb = ej_b + (size_t)ROWS_ * H_;    // 360*256
    float* bcomb = Wcomb + 360 * 256;            // 256
    float* Gbuf  = bcomb + 256;                  // 8*256*256
    float* uvec  = Gbuf + 8 * 256 * 256;         // 8*256
    float* vvec  = uvec + 8 * 256;
    float* norms = vvec + 8 * 256;               // 23040
    float* ge0   = norms + ROWS_;
    float* ge1   = ge0 + B_ * D_;

    const size_t need = (size_t)(ge1 + B_ * D_ - ws) * sizeof(float);
    if (ws_size < need) return;

    float* out    = (float*)d_out;
    float* out_ge = out;
    float* out_h  = out + (size_t)B_ * D_;
    float* out_at = out_h + (size_t)ROWS_ * D_;

    const dim3 blk(256);

    // --- node feature fusion ---
    gemm_tiled<<<dim3(4, 3), blk, 0, stream>>>(
        Wnp, Wrf, 256, 256, 256,
        nullptr, nullptr, 0, 0, 0,
        nullptr, Wcomb, 360, 256, 256, 0, 0, 0);
    biascomb_kernel<<<1, 256, 0, stream>>>(bnp, Wrf, brf, bcomb);
    gemm_tiled<<<dim3(4, 180), blk, 0, stream>>>(
        mind, Wcomb, 360, 360, 256,
        roi, Wrf + 256 * 256, 256, 256, 256,
        bcomb, s1, ROWS_, 256, 256, 0, 0, 0);          // nf -> s1
    ln_gelu_kernel<<<ROWS_, 64, 0, stream>>>(s1, ln_g, ln_b);

    // --- GAT layer 0 (dh=32) ---
    gemm_tiled<<<dim3(4, 180), blk, 0, stream>>>(
        s1, gatW0, 256, 256, 256,
        nullptr, nullptr, 0, 0, 0,
        nullptr, s2, ROWS_, 256, 256, 0, 0, 0);        // ht0 -> s2
    eiej_kernel<32><<<ROWS_, 64, 0, stream>>>(s2, gata0, ei_b, ej_b);
    gat01_agg<<<dim3(12, B_), blk, 0, stream>>>(s2, ei_b, ej_b, s3);   // h1 -> s3

    // --- GAT layer 1 (dh=32) ---
    gemm_tiled<<<dim3(4, 180), blk, 0, stream>>>(
        s3, gatW1, 256, 256, 256,
        nullptr, nullptr, 0, 0, 0,
        nullptr, s2, ROWS_, 256, 256, 0, 0, 0);        // ht1 -> s2
    eiej_kernel<32><<<ROWS_, 64, 0, stream>>>(s2, gata1, ei_b, ej_b);
    gat01_agg<<<dim3(12, B_), blk, 0, stream>>>(s2, ei_b, ej_b, s0);   // h2 -> s0

    // --- GAT layer 2 (collapsed): G_h = gatW2_h @ projW_h; out = sum_h a_h@(h2@G_h)
    gemm_tiled<<<dim3(4, 2, 8), blk, 0, stream>>>(
        gatW2, projW, 256, 2048, 256,
        nullptr, nullptr, 0, 0, 0,
        nullptr, Gbuf, 256, 256, 256,
        256, (size_t)256 * 256, (size_t)256 * 256);
    uv_kernel<<<8, 256, 0, stream>>>(gatW2, gata2, uvec, vvec);
    eiej2_kernel<<<ROWS_, 64, 0, stream>>>(s0, uvec, vvec, ei_b, ej_b);

    // heads 0-3: Z_0..3 -> s1..s4 (z-batched), then fused 4-head aggregate
    gemm_tiled<<<dim3(4, 180, 4), blk, 0, stream>>>(
        s0, Gbuf, 256, 256, 256,
        nullptr, nullptr, 0, 0, 0,
        nullptr, s1, ROWS_, 256, 256,
        0, (size_t)256 * 256, SZ);
    gat2_agg4<<<dim3(12, B_), blk, 0, stream>>>(
        s1, SZ, ei_b, ej_b, projb, out_h, 0, 1);
    // heads 4-7
    gemm_tiled<<<dim3(4, 180, 4), blk, 0, stream>>>(
        s0, Gbuf + (size_t)4 * 256 * 256, 256, 256, 256,
        nullptr, nullptr, 0, 0, 0,
        nullptr, s1, ROWS_, 256, 256,
        0, (size_t)256 * 256, SZ);
    gat2_agg4<<<dim3(12, B_), blk, 0, stream>>>(
        s1, SZ, ei_b, ej_b, projb, out_h, 4, 0);

    // --- attention readout ---
    rownorm_kernel<<<ROWS_, 64, 0, stream>>>(out_h, norms);
    softmax_n_kernel<<<B_, 64, 0, stream>>>(norms, out_at);
    ge_kernel<<<B_, 256, 0, stream>>>(out_at, out_h, ge0);
    mlp_kernel<<<B_, 256, 0, stream>>>(ge0, Wr1, br1, ge1, 1);
    mlp_kernel<<<B_, 256, 0, stream>>>(ge1, Wr2, br2, out_ge, 0);
}